// Round 5
// baseline (310.912 us; speedup 1.0000x reference)
//
#include <hip/hip_runtime.h>
#include <hip/hip_bf16.h>

typedef __attribute__((ext_vector_type(8))) short bf16x8;
typedef __attribute__((ext_vector_type(4))) float f32x4;

__device__ __forceinline__ float b2f(unsigned short u) {
  union { unsigned int i; float f; } x; x.i = ((unsigned int)u) << 16; return x.f;
}
__device__ __forceinline__ unsigned short f2b(float f) {
  union { __hip_bfloat16 h; unsigned short u; } x; x.h = __float2bfloat16(f); return x.u;
}
__device__ __forceinline__ f32x4 mfma16(bf16x8 a, bf16x8 b, f32x4 c) {
  return __builtin_amdgcn_mfma_f32_16x16x32_bf16(a, b, c, 0, 0, 0);
}
__device__ __forceinline__ void gl16(const void* g, void* l) {
  __builtin_amdgcn_global_load_lds(
      (const __attribute__((address_space(1))) unsigned int*)g,
      (__attribute__((address_space(3))) unsigned int*)l, 16, 0, 0);
}

// ---------------- cast f32 -> bf16 (vectorized) ----------------
__global__ __launch_bounds__(256) void cast_k(const float* __restrict__ src,
                                              unsigned short* __restrict__ dst, int n4) {
  int i = blockIdx.x * 256 + threadIdx.x;
  if (i >= n4) return;
  float4 v = ((const float4*)src)[i];
  ushort4 o;
  o.x = f2b(v.x); o.y = f2b(v.y); o.z = f2b(v.z); o.w = f2b(v.w);
  ((ushort4*)dst)[i] = o;
}

// =============== 256x256 8-phase bf16 GEMM (C = A * W^T), K=1024 ===============
// Register-PIPELINED revision: ds_reads issued in phase p feed the QUAD of
// phase p+1, so the LDS stream of phase p overlaps the MFMA drain of p-1.
// A-fragments ping-pong afP/afQ; bf0/bf1 are reloaded early (2-phase lifetime).
//
// QUAD schedule (regs -> QUAD): ph1 (afP,bf0)=A00xB00, ph2 (afP,bf1)=A00xB01,
// ph3 (afQ,bf0)=A01xB00, ph4 (afQ,bf1)=A01xB01, ph5-8 same on buf1.
// Load schedule (top of phase, for NEXT QUAD):
//   ph1: bf1<-B(0,1)   ph2: afQ<-A(0,1)   ph3: -      ph4: afP<-A(1,0), bf0<-B(1,0)
//   ph5: bf1<-B(1,1)   ph6: afQ<-A(1,1)   ph7: -      ph8: afP<-A(0,0)', bf0<-B(0,0)'
// Stage schedule (unchanged): ph1 A-g1(buf1,t1) ph2 B-g1(buf1,t1)
//   ph3 A-g0(buf0,t2) ph4 B-g0(buf0,t2) ph5 A-g1(buf0,t2) ph6 B-g1(buf0,t2)
//   ph7 A-g0(buf1,t3) ph8 B-g0(buf1,t3)
// vmcnt ledger (loads outstanding, 2 per STAGE): enter iter with 4 [prev ph7,8].
//   ph3-end: 10 -> vmcnt(6) drains prev ph7/ph8 (buf1-g0)  => ph4 reads safe.
//   ph4-end:  8 -> vmcnt(4) drains ph1/ph2   (buf1-g1)     => ph5/ph6 reads safe.
//   ph7-end: 10 -> vmcnt(6) drains ph3/ph4   (buf0-g0 t2)  => ph8 reads safe.
//   ph8-end:  8 -> vmcnt(4) drains ph5/ph6   (buf0-g1 t2)  => ph1'/ph2' safe.
// WAR: every LDS region has >=3 phases between last ds_read and re-stage, with
// the reader's lgkm-wait (compiler-emitted before QUAD) + barriers in between.
// Never vmcnt(0) in the loop; vmcnt(0) once after (nothing in flight at endpgm).
// Last iter re-stages tiles 14/15 (identical bytes, L2-hot) instead of 0/1.
#define BARX() asm volatile("s_barrier" ::: "memory")
#define WAITV4() asm volatile("s_waitcnt vmcnt(4)" ::: "memory")
#define WAITV6() asm volatile("s_waitcnt vmcnt(6)" ::: "memory")
#define WAITV0() asm volatile("s_waitcnt vmcnt(0)" ::: "memory")
#define P1() __builtin_amdgcn_s_setprio(1)
#define P0() __builtin_amdgcn_s_setprio(0)

#define STAGE_A(BUF, G, TAU) do { \
  gl16(gA_0 + (size_t)(G) * 65536 + (TAU) * 64, sAB + (BUF) * 32768 + (G) * 16384 + u0 * 16); \
  gl16(gA_0 + 131072 + (size_t)(G) * 65536 + (TAU) * 64, sAB + (BUF) * 32768 + (G) * 16384 + u0 * 16 + 8192); } while (0)
#define STAGE_B(BUF, G, TAU) do { \
  gl16(gB_0 + (size_t)(G) * 32768 + (TAU) * 64, sAB + 65536 + (BUF) * 32768 + (G) * 16384 + u0 * 16); \
  gl16(gB_0 + 131072 + (size_t)(G) * 32768 + (TAU) * 64, sAB + 65536 + (BUF) * 32768 + (G) * 16384 + u0 * 16 + 8192); } while (0)

#define LOADA(BUF, MH, DST) do { \
  _Pragma("unroll") for (int mi = 0; mi < 4; ++mi) { \
    const char* p_ = (const char*)sAB + (BUF) * 32768 + (MH) * 16384 + aRd + mi * 2048; \
    DST[mi][0] = *(const bf16x8*)(p_ + sr0); \
    DST[mi][1] = *(const bf16x8*)(p_ + sr1); } } while (0)
#define LOADB(BUF, NH, DST) do { \
  _Pragma("unroll") for (int ni = 0; ni < 2; ++ni) { \
    const char* p_ = (const char*)sAB + 65536 + (BUF) * 32768 + (NH) * 16384 + bRd + ni * 2048; \
    DST[ni][0] = *(const bf16x8*)(p_ + sr0); \
    DST[ni][1] = *(const bf16x8*)(p_ + sr1); } } while (0)

#define QUADX(AF, BF, MH, NH) do { \
  _Pragma("unroll") for (int mi = 0; mi < 4; ++mi) \
    _Pragma("unroll") for (int ni = 0; ni < 2; ++ni) { \
      acc[(MH) * 4 + mi][(NH) * 2 + ni] = mfma16(AF[mi][0], BF[ni][0], acc[(MH) * 4 + mi][(NH) * 2 + ni]); \
      acc[(MH) * 4 + mi][(NH) * 2 + ni] = mfma16(AF[mi][1], BF[ni][1], acc[(MH) * 4 + mi][(NH) * 2 + ni]); } } while (0)

template<int MODE>
__global__ __launch_bounds__(512, 2) void gemm256(
    const unsigned short* __restrict__ A,
    const unsigned short* __restrict__ W0, const unsigned short* __restrict__ W1,
    const unsigned short* __restrict__ W2,
    const float* __restrict__ bias0, const float* __restrict__ bias1, const float* __restrict__ bias2,
    float* __restrict__ outF,
    unsigned short* __restrict__ o0, unsigned short* __restrict__ o1, unsigned short* __restrict__ o2,
    int tiles_m)
{
  __shared__ char sAB[131072];
  int bid = blockIdx.x;
  int nwg = gridDim.x;
  int cpx = nwg >> 3;                       // nwg % 8 == 0 for all launches
  int sbid = (bid & 7) * cpx + (bid >> 3);  // XCD-aware swizzle (bijective)
  int tm = sbid % tiles_m, tn = sbid / tiles_m;
  int m0 = tm * 256, n0 = tn * 256;

  const unsigned short* W = W0; const float* bias = bias0; unsigned short* outB = o0;
  int sel = 0;
  if (MODE == 1) {
    sel = n0 >> 10;
    if (sel == 1) { W = W1; bias = bias1; outB = o1; }
    else if (sel == 2) { W = W2; bias = bias2; outB = o2; }
  }
  int nloc0 = (MODE == 1) ? (n0 & 1023) : n0;

  int t = threadIdx.x, w = t >> 6, l = t & 63;
  int wm = w >> 2, wn = w & 3;              // 2M x 4N waves

  // ---- staging per-thread constants (unit u0 = t; unit u1 = t+512 is a
  //      constant offset: lr+64 (same &7), global row +128, LDS +8192) ----
  int u0 = t;
  int lr0 = u0 >> 3;
  int sl0 = (u0 & 7) ^ (lr0 & 7);           // inverse-swizzled src slot
  int rA0 = ((lr0 >> 6) << 7) + (lr0 & 63);
  int rB0 = ((lr0 >> 5) << 6) + (lr0 & 31);
  const unsigned short* gA_0 = A + (size_t)(m0 + rA0) * 1024 + sl0 * 8;
  const unsigned short* gB_0 = W + (size_t)(nloc0 + rB0) * 1024 + sl0 * 8;

  // ---- reader constants ----
  int aRd = (wm * 64 + (l & 15)) * 128;
  int bRd = (wn * 32 + (l & 15)) * 128;
  int sr0 = (((l >> 4) + 0) ^ (l & 7)) * 16;  // ks=0 swizzled slot
  int sr1 = (((l >> 4) + 4) ^ (l & 7)) * 16;  // ks=1

  f32x4 acc[8][4];
  f32x4 zero = {0.f, 0.f, 0.f, 0.f};
#pragma unroll
  for (int i = 0; i < 8; ++i)
#pragma unroll
    for (int jx = 0; jx < 4; ++jx) acc[i][jx] = zero;
  bf16x8 afP[4][2], afQ[4][2], bf0[2][2], bf1[2][2];

  // ---- prologue: stage tile0 (4 granules) + tile1 g0; preload ph1 frags ----
  STAGE_A(0, 0, 0); STAGE_B(0, 0, 0); STAGE_A(0, 1, 0); STAGE_B(0, 1, 0);
  STAGE_A(1, 0, 1); STAGE_B(1, 0, 1);
  WAITV4();   // tile0 fully landed ([tile1-g0 A,B] = 4 in flight)
  BARX();
  LOADA(0, 0, afP); LOADB(0, 0, bf0);

  for (int j = 0; j < 8; ++j) {
    int t1 = 2 * j + 1;
    int t2 = (j < 7) ? (2 * j + 2) : 14;  // last iter: re-stage L2-hot tiles
    int t3 = (j < 7) ? (2 * j + 3) : 15;  // (identical bytes -> benign)
    // ph1
    LOADB(0, 1, bf1);
    STAGE_A(1, 1, t1);
    BARX(); P1(); QUADX(afP, bf0, 0, 0); P0(); BARX();
    // ph2
    LOADA(0, 1, afQ);
    STAGE_B(1, 1, t1);
    BARX(); P1(); QUADX(afP, bf1, 0, 1); P0(); BARX();
    // ph3
    STAGE_A(0, 0, t2);
    BARX(); P1(); QUADX(afQ, bf0, 1, 0); P0(); WAITV6(); BARX();
    // ph4
    LOADA(1, 0, afP); LOADB(1, 0, bf0);
    STAGE_B(0, 0, t2);
    BARX(); P1(); QUADX(afQ, bf1, 1, 1); P0(); WAITV4(); BARX();
    // ph5
    LOADB(1, 1, bf1);
    STAGE_A(0, 1, t2);
    BARX(); P1(); QUADX(afP, bf0, 0, 0); P0(); BARX();
    // ph6
    LOADA(1, 1, afQ);
    STAGE_B(0, 1, t2);
    BARX(); P1(); QUADX(afP, bf1, 0, 1); P0(); BARX();
    // ph7
    STAGE_A(1, 0, t3);
    BARX(); P1(); QUADX(afQ, bf0, 1, 0); P0(); WAITV6(); BARX();
    // ph8
    LOADA(0, 0, afP); LOADB(0, 0, bf0);
    STAGE_B(1, 0, t3);
    BARX(); P1(); QUADX(afQ, bf1, 1, 1); P0(); WAITV4(); BARX();
  }
  WAITV0();  // no global_load_lds in flight at s_endpgm / during epilogue

  // ---- epilogue ----
#pragma unroll
  for (int mq = 0; mq < 8; ++mq) {
    int grow = m0 + wm * 128 + (mq >> 2) * 64 + (mq & 3) * 16 + ((l >> 4) << 2);
#pragma unroll
    for (int nq = 0; nq < 4; ++nq) {
      int gcol = n0 + wn * 64 + (nq >> 1) * 32 + (nq & 1) * 16 + (l & 15);
      if (MODE == 0) {
        float bb = bias[gcol];
#pragma unroll
        for (int r = 0; r < 4; ++r)
          outF[(size_t)(grow + r) * 1024 + gcol] = acc[mq][nq][r] + bb;
      } else {
        int c = gcol & 1023;
        float bb = bias[c];
#pragma unroll
        for (int r = 0; r < 4; ++r) {
          float v = acc[mq][nq][r] + bb;
          if (sel < 2) v = (v > 0.0f) ? (v + 1.0f) : __expf(v);  // elu(x)+1
          outB[(size_t)(grow + r) * 1024 + c] = f2b(v);
        }
      }
    }
  }
}

// ---------------- per-head transpose: (b,n,h,d) -> [bh][d][n], optional k_sum ----------------
template<int DOSUM>
__global__ __launch_bounds__(256) void transpose_hd(
    const unsigned short* __restrict__ in,   // (16384, 1024)
    unsigned short* __restrict__ out,        // [64][64][4096]
    float* __restrict__ ksum)                // [64][64]
{
  int bid = blockIdx.x;
  int bh = bid >> 6, nt = bid & 63;
  int b = bh >> 4, h = bh & 15;
  int n0 = nt << 6;
  __shared__ unsigned short lds[64][72];
  int t = threadIdx.x;
  int rr = t >> 3, cc = (t & 7) << 3;
#pragma unroll
  for (int p = 0; p < 2; ++p) {
    int n = rr + p * 32;
    const unsigned short* src = in + ((size_t)(b * 4096 + n0 + n) * 1024 + h * 64 + cc);
    *(bf16x8*)&lds[n][cc] = *(const bf16x8*)src;
  }
  __syncthreads();
#pragma unroll
  for (int p = 0; p < 2; ++p) {
    int d = rr + p * 32;
    union { bf16x8 v; unsigned short u[8]; } pk;
    float s = 0.f;
#pragma unroll
    for (int j = 0; j < 8; ++j) {
      unsigned short uv = lds[cc + j][d];
      pk.u[j] = uv;
      if (DOSUM) s += b2f(uv);
    }
    *(bf16x8*)(out + ((size_t)bh * 64 + d) * 4096 + n0 + cc) = pk.v;
    if (DOSUM) {
      s += __shfl_xor(s, 1);
      s += __shfl_xor(s, 2);
      s += __shfl_xor(s, 4);
      if ((t & 7) == 0) atomicAdd(ksum + bh * 64 + d, s);
    }
  }
}

// ---------------- context: ctxT[bh][e][d] = sum_n v[n,e]*k[n,d], split-K over n ----------------
__global__ __launch_bounds__(64) void ctx_gemm(
    const unsigned short* __restrict__ vT,  // [bh][64][4096]
    const unsigned short* __restrict__ kT,  // [bh][64][4096]
    float* __restrict__ ctxT)               // [bh][64][64]
{
  int bid = blockIdx.x;
  int bh = bid >> 3, ch = bid & 7;
  int l = threadIdx.x;
  const unsigned short* aB = vT + ((size_t)bh * 64 + (l & 15)) * 4096 + ch * 512 + ((l >> 4) << 3);
  const unsigned short* bB = kT + ((size_t)bh * 64 + (l & 15)) * 4096 + ch * 512 + ((l >> 4) << 3);
  f32x4 acc[4][4];
  f32x4 zero = {0.f, 0.f, 0.f, 0.f};
#pragma unroll
  for (int i = 0; i < 4; ++i)
#pragma unroll
    for (int j = 0; j < 4; ++j) acc[i][j] = zero;
  for (int ks = 0; ks < 16; ++ks) {
    bf16x8 av[4], bv[4];
#pragma unroll
    for (int mi = 0; mi < 4; ++mi) av[mi] = *(const bf16x8*)(aB + (size_t)mi * 16 * 4096 + ks * 32);
#pragma unroll
    for (int ni = 0; ni < 4; ++ni) bv[ni] = *(const bf16x8*)(bB + (size_t)ni * 16 * 4096 + ks * 32);
#pragma unroll
    for (int mi = 0; mi < 4; ++mi)
#pragma unroll
      for (int ni = 0; ni < 4; ++ni)
        acc[mi][ni] = mfma16(av[mi], bv[ni], acc[mi][ni]);
  }
#pragma unroll
  for (int mi = 0; mi < 4; ++mi)
#pragma unroll
    for (int ni = 0; ni < 4; ++ni)
#pragma unroll
      for (int r = 0; r < 4; ++r) {
        int e = mi * 16 + ((l >> 4) << 2) + r;
        int d = ni * 16 + (l & 15);
        atomicAdd(ctxT + (size_t)bh * 4096 + e * 64 + d, acc[mi][ni][r]);
      }
}

// ---------------- D_inv = 1/(q . k_sum + eps) ----------------
__global__ __launch_bounds__(256) void denom_k(
    const unsigned short* __restrict__ q,
    const float* __restrict__ ksum,
    float* __restrict__ dinv)
{
  int t = threadIdx.x, w = t >> 6, l = t & 63;
  int idx = blockIdx.x * 4 + w;
  int b = idx >> 12;
  int h = l >> 2, part = l & 3;
  const unsigned short* qp = q + (size_t)idx * 1024 + h * 64 + part * 16;
  const float* kp = ksum + ((b << 4) + h) * 64 + part * 16;
  bf16x8 v0 = *(const bf16x8*)qp;
  bf16x8 v1 = *(const bf16x8*)(qp + 8);
  float s = 0.f;
#pragma unroll
  for (int j = 0; j < 8; ++j) s += b2f((unsigned short)v0[j]) * kp[j];
#pragma unroll
  for (int j = 0; j < 8; ++j) s += b2f((unsigned short)v1[j]) * kp[8 + j];
  s += __shfl_xor(s, 1);
  s += __shfl_xor(s, 2);
  if (part == 0) dinv[(size_t)idx * 16 + h] = 1.0f / (s + 1e-6f);
}

// ---------------- att = (q @ ctx) * D_inv, written in-place into q ----------------
__global__ __launch_bounds__(256) void att_gemm(
    unsigned short* __restrict__ q,      // (16384,1024) in/out
    const float* __restrict__ ctxT,      // [bh][e][d]
    const float* __restrict__ dinv)      // [16384][16]
{
  int bid = blockIdx.x;
  int bh = bid & 63, mt = bid >> 6;
  int b = bh >> 4, h = bh & 15;
  int t = threadIdx.x, w = t >> 6, l = t & 63;
  int m0 = mt * 256 + w * 64;

  bf16x8 bfr[2][4];
  const float* cb = ctxT + (size_t)bh * 4096;
#pragma unroll
  for (int ks = 0; ks < 2; ++ks)
#pragma unroll
    for (int ni = 0; ni < 4; ++ni) {
      const float* p = cb + (ni * 16 + (l & 15)) * 64 + ks * 32 + ((l >> 4) << 3);
#pragma unroll
      for (int j = 0; j < 8; ++j) bfr[ks][ni][j] = (short)f2b(p[j]);
    }

  f32x4 acc[4][4];
  f32x4 zero = {0.f, 0.f, 0.f, 0.f};
#pragma unroll
  for (int i = 0; i < 4; ++i)
#pragma unroll
    for (int j = 0; j < 4; ++j) acc[i][j] = zero;

  size_t rowbase = (size_t)(b * 4096 + m0 + (l & 15)) * 1024 + h * 64 + ((l >> 4) << 3);
#pragma unroll
  for (int mi = 0; mi < 4; ++mi) {
#pragma unroll
    for (int ks = 0; ks < 2; ++ks) {
      bf16x8 av = *(const bf16x8*)(q + rowbase + (size_t)mi * 16 * 1024 + ks * 32);
#pragma unroll
      for (int ni = 0; ni < 4; ++ni) acc[mi][ni] = mfma16(av, bfr[ks][ni], acc[mi][ni]);
    }
  }

#pragma unroll
  for (int mi = 0; mi < 4; ++mi)
#pragma unroll
    for (int ni = 0; ni < 4; ++ni) {
      int e = ni * 16 + (l & 15);
#pragma unroll
      for (int r = 0; r < 4; ++r) {
        int npos = m0 + mi * 16 + ((l >> 4) << 2) + r;
        float sc = dinv[(size_t)(b * 4096 + npos) * 16 + h];
        q[(size_t)(b * 4096 + npos) * 1024 + h * 64 + e] = f2b(acc[mi][ni][r] * sc);
      }
    }
}

extern "C" void kernel_launch(void* const* d_in, const int* in_sizes, int n_in,
                              void* d_out, int out_size, void* d_ws, size_t ws_size,
                              hipStream_t stream)
{
  const float* x  = (const float*)d_in[0];
  const float* bq = (const float*)d_in[2];
  const float* bk = (const float*)d_in[4];
  const float* bv = (const float*)d_in[6];
  const float* bo = (const float*)d_in[8];
  const float* Wq = (const float*)d_in[1];
  const float* Wk = (const float*)d_in[3];
  const float* Wv = (const float*)d_in[5];
  const float* Wo = (const float*)d_in[7];
  float* out = (float*)d_out;

  char* ws = (char*)d_ws;
  const size_t SB = (size_t)16384 * 1024 * 2;  // 32 MiB slab
  const size_t NEED = 4 * SB + 4 * (1u << 21) + 2 * (1u << 20) + (1u << 14);
  if (ws_size < NEED) return;  // signature: absmax == max|ref| ~ 6.4e-2

  unsigned short* xb  = (unsigned short*)(ws);           // x bf16; later vT
  unsigned short* qb  = (unsigned short*)(ws + SB);      // q bf16; later att
  unsigned short* kb  = (unsigned short*)(ws + 2 * SB);  // k bf16
  unsigned short* vb  = (unsigned short*)(ws + 3 * SB);  // v bf16; later kT
  unsigned short* wqb = (unsigned short*)(ws + 4 * SB);
  unsigned short* wkb = (unsigned short*)(ws + 4 * SB + (1u << 21));
  unsigned short* wvb = (unsigned short*)(ws + 4 * SB + (2u << 21));
  unsigned short* wob = (unsigned short*)(ws + 4 * SB + (3u << 21));
  float* ctxT = (float*)(ws + 4 * SB + (4u << 21));
  float* dinv = (float*)(ws + 4 * SB + (4u << 21) + (1u << 20));
  float* ksum = (float*)(ws + 4 * SB + (4u << 21) + (2u << 20));

  hipMemsetAsync(ctxT, 0, 64 * 64 * 64 * 4, stream);
  hipMemsetAsync(ksum, 0, 64 * 64 * 4, stream);

  cast_k<<<16384, 256, 0, stream>>>(x, xb, 16777216 / 4);
  cast_k<<<1024, 256, 0, stream>>>(Wq, wqb, 1048576 / 4);
  cast_k<<<1024, 256, 0, stream>>>(Wk, wkb, 1048576 / 4);
  cast_k<<<1024, 256, 0, stream>>>(Wv, wvb, 1048576 / 4);
  cast_k<<<1024, 256, 0, stream>>>(Wo, wob, 1048576 / 4);

  // QKV: (16384 x 1024) @ (3072 x 1024)^T, fused bias + elu+1 on q,k
  gemm256<1><<<768, 512, 0, stream>>>(xb, wqb, wkb, wvb, bq, bk, bv,
                                      nullptr, qb, kb, vb, 64);

  transpose_hd<0><<<4096, 256, 0, stream>>>(vb, xb, nullptr);  // vT -> xb
  transpose_hd<1><<<4096, 256, 0, stream>>>(kb, vb, ksum);     // kT -> vb, k_sum

  ctx_gemm<<<512, 64, 0, stream>>>(xb, vb, ctxT);

  denom_k<<<4096, 256, 0, stream>>>(qb, ksum, dinv);

  att_gemm<<<1024, 256, 0, stream>>>(qb, ctxT, dinv);          // att -> qb (in place)

  // final: att @ Wo^T + bo -> f32 out
  gemm256<0><<<256, 512, 0, stream>>>(qb, wob, nullptr, nullptr, bo, nullptr, nullptr,
                                      out, nullptr, nullptr, nullptr, 64);
}

// Round 6
// 262.423 us; speedup vs baseline: 1.1848x; 1.1848x over previous
//
#include <hip/hip_runtime.h>
#include <hip/hip_bf16.h>

typedef __attribute__((ext_vector_type(8))) short bf16x8;
typedef __attribute__((ext_vector_type(4))) float f32x4;

__device__ __forceinline__ float b2f(unsigned short u) {
  union { unsigned int i; float f; } x; x.i = ((unsigned int)u) << 16; return x.f;
}
__device__ __forceinline__ unsigned short f2b(float f) {
  union { __hip_bfloat16 h; unsigned short u; } x; x.h = __float2bfloat16(f); return x.u;
}
__device__ __forceinline__ f32x4 mfma16(bf16x8 a, bf16x8 b, f32x4 c) {
  return __builtin_amdgcn_mfma_f32_16x16x32_bf16(a, b, c, 0, 0, 0);
}
__device__ __forceinline__ void gl16(const void* g, void* l) {
  __builtin_amdgcn_global_load_lds(
      (const __attribute__((address_space(1))) unsigned int*)g,
      (__attribute__((address_space(3))) unsigned int*)l, 16, 0, 0);
}

// ---------------- cast f32 -> bf16 (vectorized) ----------------
__global__ __launch_bounds__(256) void cast_k(const float* __restrict__ src,
                                              unsigned short* __restrict__ dst, int n4) {
  int i = blockIdx.x * 256 + threadIdx.x;
  if (i >= n4) return;
  float4 v = ((const float4*)src)[i];
  ushort4 o;
  o.x = f2b(v.x); o.y = f2b(v.y); o.z = f2b(v.z); o.w = f2b(v.w);
  ((ushort4*)dst)[i] = o;
}

// =============== 256x256 8-phase bf16 GEMM (C = A * W^T), K=1024 ===============
// K-loop = the R4-proven schedule (same-phase ds_read consume, LGKM0 after
// barrier, counted vmcnt(4), setprio) — the R5 cross-phase register pipeline
// REGRESSED (152us vs 119.7us) and is reverted.
// MODE 0: f32 out + bias (final projection, N=1024)
// MODE 1: QKV fused (N=3072): sel=0 q -> row-major bf16 + elu+1;
//         sel=1 k -> elu+1, written TRANSPOSED [bh][d][n] + ksum atomics;
//         sel=2 v -> written TRANSPOSED [bh][d][n].
// Transposed epilogue: acc -> LDS [256 cols][256 rows] bf16 with XOR swizzle
// (byte = c*512 + ((r*2)^((c&7)<<4))), barrier, column reads (b128) ->
// coalesced global stores along n. ksum fused on the read pass (8-lane reduce).
#define BARX() asm volatile("s_barrier" ::: "memory")
#define LGKM0() asm volatile("s_waitcnt lgkmcnt(0)" ::: "memory")
#define WAITV4() asm volatile("s_waitcnt vmcnt(4)" ::: "memory")
#define WAITV0() asm volatile("s_waitcnt vmcnt(0)" ::: "memory")
#define P1() __builtin_amdgcn_s_setprio(1)
#define P0() __builtin_amdgcn_s_setprio(0)

#define STAGE_A(BUF, G, TAU) do { \
  gl16(gA_0 + (size_t)(G) * 65536 + (TAU) * 64, sAB + (BUF) * 32768 + (G) * 16384 + u0 * 16); \
  gl16(gA_1 + (size_t)(G) * 65536 + (TAU) * 64, sAB + (BUF) * 32768 + (G) * 16384 + u1 * 16); } while (0)
#define STAGE_B(BUF, G, TAU) do { \
  gl16(gB_0 + (size_t)(G) * 32768 + (TAU) * 64, sAB + 65536 + (BUF) * 32768 + (G) * 16384 + u0 * 16); \
  gl16(gB_1 + (size_t)(G) * 32768 + (TAU) * 64, sAB + 65536 + (BUF) * 32768 + (G) * 16384 + u1 * 16); } while (0)

#define LOAD_A(BUF, MH) do { \
  _Pragma("unroll") for (int mi = 0; mi < 4; ++mi) { \
    const char* p_ = (const char*)sAB + (BUF) * 32768 + (MH) * 16384 + aRd + mi * 2048; \
    af[mi][0] = *(const bf16x8*)(p_ + sr0); \
    af[mi][1] = *(const bf16x8*)(p_ + sr1); } } while (0)
#define LOAD_B(BUF, NH, DST) do { \
  _Pragma("unroll") for (int ni = 0; ni < 2; ++ni) { \
    const char* p_ = (const char*)sAB + 65536 + (BUF) * 32768 + (NH) * 16384 + bRd + ni * 2048; \
    DST[ni][0] = *(const bf16x8*)(p_ + sr0); \
    DST[ni][1] = *(const bf16x8*)(p_ + sr1); } } while (0)

#define QUAD(MH, NH, BF) do { \
  _Pragma("unroll") for (int mi = 0; mi < 4; ++mi) \
    _Pragma("unroll") for (int ni = 0; ni < 2; ++ni) { \
      acc[(MH) * 4 + mi][(NH) * 2 + ni] = mfma16(af[mi][0], BF[ni][0], acc[(MH) * 4 + mi][(NH) * 2 + ni]); \
      acc[(MH) * 4 + mi][(NH) * 2 + ni] = mfma16(af[mi][1], BF[ni][1], acc[(MH) * 4 + mi][(NH) * 2 + ni]); } } while (0)

template<int MODE>
__global__ __launch_bounds__(512, 2) void gemm256(
    const unsigned short* __restrict__ A,
    const unsigned short* __restrict__ W0, const unsigned short* __restrict__ W1,
    const unsigned short* __restrict__ W2,
    const float* __restrict__ bias0, const float* __restrict__ bias1, const float* __restrict__ bias2,
    float* __restrict__ outF,
    unsigned short* __restrict__ o0, unsigned short* __restrict__ o1, unsigned short* __restrict__ o2,
    int tiles_m, float* __restrict__ ksum)
{
  __shared__ char sAB[131072];
  int bid = blockIdx.x;
  int nwg = gridDim.x;
  int cpx = nwg >> 3;                       // nwg % 8 == 0 for all launches
  int sbid = (bid & 7) * cpx + (bid >> 3);  // XCD-aware swizzle (bijective)
  int tm = sbid % tiles_m, tn = sbid / tiles_m;
  int m0 = tm * 256, n0 = tn * 256;

  const unsigned short* W = W0; const float* bias = bias0; unsigned short* outB = o0;
  int sel = 0;
  if (MODE == 1) {
    sel = n0 >> 10;
    if (sel == 1) { W = W1; bias = bias1; outB = o1; }
    else if (sel == 2) { W = W2; bias = bias2; outB = o2; }
  }
  int nloc0 = (MODE == 1) ? (n0 & 1023) : n0;

  int t = threadIdx.x, w = t >> 6, l = t & 63;
  int wm = w >> 2, wn = w & 3;              // 2M x 4N waves

  // ---- staging per-thread constants (2 x 16B units per granule) ----
  int u0 = t, u1 = t + 512;
  int lr0 = u0 >> 3, lr1 = u1 >> 3;
  int sl0 = (u0 & 7) ^ (lr0 & 7), sl1 = (u1 & 7) ^ (lr1 & 7);  // inverse-swizzled src slot
  int rA0 = ((lr0 >> 6) << 7) + (lr0 & 63), rA1 = ((lr1 >> 6) << 7) + (lr1 & 63);
  int rB0 = ((lr0 >> 5) << 6) + (lr0 & 31), rB1 = ((lr1 >> 5) << 6) + (lr1 & 31);
  const unsigned short* gA_0 = A + (size_t)(m0 + rA0) * 1024 + sl0 * 8;
  const unsigned short* gA_1 = A + (size_t)(m0 + rA1) * 1024 + sl1 * 8;
  const unsigned short* gB_0 = W + (size_t)(nloc0 + rB0) * 1024 + sl0 * 8;
  const unsigned short* gB_1 = W + (size_t)(nloc0 + rB1) * 1024 + sl1 * 8;

  // ---- reader constants ----
  int aRd = (wm * 64 + (l & 15)) * 128;
  int bRd = (wn * 32 + (l & 15)) * 128;
  int sr0 = (((l >> 4) + 0) ^ (l & 7)) * 16;  // ks=0 swizzled slot
  int sr1 = (((l >> 4) + 4) ^ (l & 7)) * 16;  // ks=1

  f32x4 acc[8][4];
  f32x4 zero = {0.f, 0.f, 0.f, 0.f};
#pragma unroll
  for (int i = 0; i < 8; ++i)
#pragma unroll
    for (int jx = 0; jx < 4; ++jx) acc[i][jx] = zero;
  bf16x8 af[4][2], bf0[2][2], bf1[2][2];

  // ---- prologue: tile0 (4 granules) + tile1 (A-g0, B-g0) ----
  STAGE_A(0, 0, 0); STAGE_B(0, 0, 0); STAGE_A(0, 1, 0); STAGE_B(0, 1, 0);
  STAGE_A(1, 0, 1); STAGE_B(1, 0, 1);
  WAITV4();   // tile0 fully landed (2 granules of tile1 in flight)
  BARX();

  for (int j = 0; j < 8; ++j) {
    int t1 = 2 * j + 1;
    int t2 = (j < 7) ? (2 * j + 2) : 14;  // last iter: re-stage L2-hot tiles
    int t3 = (j < 7) ? (2 * j + 3) : 15;  // (identical bytes -> benign)
    // ph1
    LOAD_A(0, 0); LOAD_B(0, 0, bf0);
    STAGE_A(1, 1, t1);
    BARX(); LGKM0(); P1(); QUAD(0, 0, bf0); P0(); BARX();
    // ph2
    LOAD_B(0, 1, bf1);
    STAGE_B(1, 1, t1);
    BARX(); LGKM0(); P1(); QUAD(0, 1, bf1); P0(); BARX();
    // ph3
    LOAD_A(0, 1);
    STAGE_A(0, 0, t2);
    BARX(); LGKM0(); P1(); QUAD(1, 0, bf0); P0(); BARX();
    // ph4
    STAGE_B(0, 0, t2);
    BARX(); LGKM0(); P1(); QUAD(1, 1, bf1); P0(); WAITV4(); BARX();
    // ph5
    LOAD_A(1, 0); LOAD_B(1, 0, bf0);
    STAGE_A(0, 1, t2);
    BARX(); LGKM0(); P1(); QUAD(0, 0, bf0); P0(); BARX();
    // ph6
    LOAD_B(1, 1, bf1);
    STAGE_B(0, 1, t2);
    BARX(); LGKM0(); P1(); QUAD(0, 1, bf1); P0(); BARX();
    // ph7
    LOAD_A(1, 1);
    STAGE_A(1, 0, t3);
    BARX(); LGKM0(); P1(); QUAD(1, 0, bf0); P0(); BARX();
    // ph8
    STAGE_B(1, 0, t3);
    BARX(); LGKM0(); P1(); QUAD(1, 1, bf1); P0(); WAITV4(); BARX();
  }
  WAITV0();  // no global_load_lds in flight at s_endpgm / during epilogue

  // ---- epilogue ----
  if (MODE == 1 && sel >= 1) {
    // k/v: write TRANSPOSED [bh][d][n] via in-LDS 256x256 transpose.
    int b_idx = m0 >> 12;
    int nloc_h = nloc0 >> 6;
    // pass A: acc -> LDS (col-major-ish, XOR-swizzled rows)
#pragma unroll
    for (int mq = 0; mq < 8; ++mq) {
      int r_base = wm * 128 + (mq >> 2) * 64 + (mq & 3) * 16 + ((l >> 4) << 2);
#pragma unroll
      for (int nq = 0; nq < 4; ++nq) {
        int c_loc = wn * 64 + (nq >> 1) * 32 + (nq & 1) * 16 + (l & 15);
        float bb = bias[nloc0 + c_loc];
        float v0 = acc[mq][nq][0] + bb, v1 = acc[mq][nq][1] + bb;
        float v2 = acc[mq][nq][2] + bb, v3 = acc[mq][nq][3] + bb;
        if (sel == 1) {  // elu(x)+1 for k
          v0 = (v0 > 0.0f) ? (v0 + 1.0f) : __expf(v0);
          v1 = (v1 > 0.0f) ? (v1 + 1.0f) : __expf(v1);
          v2 = (v2 > 0.0f) ? (v2 + 1.0f) : __expf(v2);
          v3 = (v3 > 0.0f) ? (v3 + 1.0f) : __expf(v3);
        }
        unsigned long long pk =
            (unsigned long long)(f2b(v0) | ((unsigned int)f2b(v1) << 16)) |
            ((unsigned long long)(f2b(v2) | ((unsigned int)f2b(v3) << 16)) << 32);
        int byte = c_loc * 512 + ((r_base * 2) ^ ((c_loc & 7) << 4));
        *(unsigned long long*)(sAB + byte) = pk;
      }
    }
    __syncthreads();
    // pass B: column reads -> coalesced global stores along n (+ ksum for k)
#pragma unroll
    for (int p = 0; p < 4; ++p) {
      int c_loc = p * 64 + w * 8 + (l >> 3);
      int n_off = (l & 7) * 32;
      int d = c_loc & 63;
      int bh = b_idx * 16 + nloc_h + (c_loc >> 6);
      unsigned short* dst = outB + (size_t)(bh * 64 + d) * 4096 + (m0 & 4095) + n_off;
      float s = 0.f;
#pragma unroll
      for (int i = 0; i < 4; ++i) {
        int byte = c_loc * 512 + (((n_off + i * 8) * 2) ^ ((c_loc & 7) << 4));
        bf16x8 ch = *(const bf16x8*)(sAB + byte);
        if (sel == 1) {
#pragma unroll
          for (int jj = 0; jj < 8; ++jj) s += b2f((unsigned short)ch[jj]);
        }
        *(bf16x8*)(dst + i * 8) = ch;
      }
      if (sel == 1) {
        s += __shfl_xor(s, 1);
        s += __shfl_xor(s, 2);
        s += __shfl_xor(s, 4);
        if ((l & 7) == 0) atomicAdd(ksum + bh * 64 + d, s);
      }
    }
  } else {
#pragma unroll
    for (int mq = 0; mq < 8; ++mq) {
      int grow = m0 + wm * 128 + (mq >> 2) * 64 + (mq & 3) * 16 + ((l >> 4) << 2);
#pragma unroll
      for (int nq = 0; nq < 4; ++nq) {
        int gcol = n0 + wn * 64 + (nq >> 1) * 32 + (nq & 1) * 16 + (l & 15);
        if (MODE == 0) {
          float bb = bias[gcol];
#pragma unroll
          for (int r = 0; r < 4; ++r)
            outF[(size_t)(grow + r) * 1024 + gcol] = acc[mq][nq][r] + bb;
        } else {  // sel == 0: q, row-major + elu+1
          int c = gcol & 1023;
          float bb = bias[c];
#pragma unroll
          for (int r = 0; r < 4; ++r) {
            float v = acc[mq][nq][r] + bb;
            v = (v > 0.0f) ? (v + 1.0f) : __expf(v);
            outB[(size_t)(grow + r) * 1024 + c] = f2b(v);
          }
        }
      }
    }
  }
}

// ---------------- context: ctxT[bh][e][d] = sum_n v[n,e]*k[n,d], split-K over n ----------------
__global__ __launch_bounds__(64) void ctx_gemm(
    const unsigned short* __restrict__ vT,  // [bh][64][4096]
    const unsigned short* __restrict__ kT,  // [bh][64][4096]
    float* __restrict__ ctxT)               // [bh][64][64]
{
  int bid = blockIdx.x;
  int bh = bid >> 3, ch = bid & 7;
  int l = threadIdx.x;
  const unsigned short* aB = vT + ((size_t)bh * 64 + (l & 15)) * 4096 + ch * 512 + ((l >> 4) << 3);
  const unsigned short* bB = kT + ((size_t)bh * 64 + (l & 15)) * 4096 + ch * 512 + ((l >> 4) << 3);
  f32x4 acc[4][4];
  f32x4 zero = {0.f, 0.f, 0.f, 0.f};
#pragma unroll
  for (int i = 0; i < 4; ++i)
#pragma unroll
    for (int j = 0; j < 4; ++j) acc[i][j] = zero;
  for (int ks = 0; ks < 16; ++ks) {
    bf16x8 av[4], bv[4];
#pragma unroll
    for (int mi = 0; mi < 4; ++mi) av[mi] = *(const bf16x8*)(aB + (size_t)mi * 16 * 4096 + ks * 32);
#pragma unroll
    for (int ni = 0; ni < 4; ++ni) bv[ni] = *(const bf16x8*)(bB + (size_t)ni * 16 * 4096 + ks * 32);
#pragma unroll
    for (int mi = 0; mi < 4; ++mi)
#pragma unroll
      for (int ni = 0; ni < 4; ++ni)
        acc[mi][ni] = mfma16(av[mi], bv[ni], acc[mi][ni]);
  }
#pragma unroll
  for (int mi = 0; mi < 4; ++mi)
#pragma unroll
    for (int ni = 0; ni < 4; ++ni)
#pragma unroll
      for (int r = 0; r < 4; ++r) {
        int e = mi * 16 + ((l >> 4) << 2) + r;
        int d = ni * 16 + (l & 15);
        atomicAdd(ctxT + (size_t)bh * 4096 + e * 64 + d, acc[mi][ni][r]);
      }
}

// ---------------- att = (q @ ctx) * D_inv, D_inv fused; written in-place into q ----------------
__global__ __launch_bounds__(256) void att_gemm(
    unsigned short* __restrict__ q,      // (16384,1024) in/out
    const float* __restrict__ ctxT,      // [bh][e][d]
    const float* __restrict__ ksum)      // [bh][64]
{
  int bid = blockIdx.x;
  int bh = bid & 63, mt = bid >> 6;
  int b = bh >> 4, h = bh & 15;
  int t = threadIdx.x, w = t >> 6, l = t & 63;
  int m0 = mt * 256 + w * 64;

  bf16x8 bfr[2][4];
  const float* cb = ctxT + (size_t)bh * 4096;
#pragma unroll
  for (int ks = 0; ks < 2; ++ks)
#pragma unroll
    for (int ni = 0; ni < 4; ++ni) {
      const float* p = cb + (ni * 16 + (l & 15)) * 64 + ks * 32 + ((l >> 4) << 3);
#pragma unroll
      for (int j = 0; j < 8; ++j) bfr[ks][ni][j] = (short)f2b(p[j]);
    }

  const float* kp = ksum + bh * 64 + ((l >> 4) << 3);
  float kp0[8], kp1[8];
#pragma unroll
  for (int j = 0; j < 8; ++j) { kp0[j] = kp[j]; kp1[j] = kp[j + 32]; }

  f32x4 acc[4][4];
  f32x4 zero = {0.f, 0.f, 0.f, 0.f};
#pragma unroll
  for (int i = 0; i < 4; ++i)
#pragma unroll
    for (int j = 0; j < 4; ++j) acc[i][j] = zero;
  float dvv[4];

  size_t rowbase = (size_t)(b * 4096 + m0 + (l & 15)) * 1024 + h * 64 + ((l >> 4) << 3);
#pragma unroll
  for (int mi = 0; mi < 4; ++mi) {
    bf16x8 av0 = *(const bf16x8*)(q + rowbase + (size_t)mi * 16 * 1024);
    bf16x8 av1 = *(const bf16x8*)(q + rowbase + (size_t)mi * 16 * 1024 + 32);
    float s = 0.f;
#pragma unroll
    for (int j = 0; j < 8; ++j) {
      s += b2f((unsigned short)av0[j]) * kp0[j];
      s += b2f((unsigned short)av1[j]) * kp1[j];
    }
    s += __shfl_xor(s, 16);
    s += __shfl_xor(s, 32);
    dvv[mi] = 1.0f / (s + 1e-6f);
#pragma unroll
    for (int ni = 0; ni < 4; ++ni) {
      acc[mi][ni] = mfma16(av0, bfr[0][ni], acc[mi][ni]);
      acc[mi][ni] = mfma16(av1, bfr[1][ni], acc[mi][ni]);
    }
  }

#pragma unroll
  for (int mi = 0; mi < 4; ++mi) {
    float sc[4];
#pragma unroll
    for (int r = 0; r < 4; ++r) sc[r] = __shfl(dvv[mi], ((l >> 4) << 2) + r);
#pragma unroll
    for (int ni = 0; ni < 4; ++ni) {
      int e = ni * 16 + (l & 15);
#pragma unroll
      for (int r = 0; r < 4; ++r) {
        int npos = m0 + mi * 16 + ((l >> 4) << 2) + r;
        q[(size_t)(b * 4096 + npos) * 1024 + h * 64 + e] = f2b(acc[mi][ni][r] * sc[r]);
      }
    }
  }
}

extern "C" void kernel_launch(void* const* d_in, const int* in_sizes, int n_in,
                              void* d_out, int out_size, void* d_ws, size_t ws_size,
                              hipStream_t stream)
{
  const float* x  = (const float*)d_in[0];
  const float* bq = (const float*)d_in[2];
  const float* bk = (const float*)d_in[4];
  const float* bv = (const float*)d_in[6];
  const float* bo = (const float*)d_in[8];
  const float* Wq = (const float*)d_in[1];
  const float* Wk = (const float*)d_in[3];
  const float* Wv = (const float*)d_in[5];
  const float* Wo = (const float*)d_in[7];
  float* out = (float*)d_out;

  char* ws = (char*)d_ws;
  const size_t SB = (size_t)16384 * 1024 * 2;  // 32 MiB slab
  const size_t NEED = 4 * SB + 4 * (1u << 21) + 2 * (1u << 20) + (1u << 14);
  if (ws_size < NEED) return;  // signature: absmax == max|ref| ~ 6.4e-2

  unsigned short* xb  = (unsigned short*)(ws);           // x bf16 (GEMM A input)
  unsigned short* qb  = (unsigned short*)(ws + SB);      // q bf16 row-major; later att
  unsigned short* kTb = (unsigned short*)(ws + 2 * SB);  // kT [bh][d][n]
  unsigned short* vTb = (unsigned short*)(ws + 3 * SB);  // vT [bh][d][n]
  unsigned short* wqb = (unsigned short*)(ws + 4 * SB);
  unsigned short* wkb = (unsigned short*)(ws + 4 * SB + (1u << 21));
  unsigned short* wvb = (unsigned short*)(ws + 4 * SB + (2u << 21));
  unsigned short* wob = (unsigned short*)(ws + 4 * SB + (3u << 21));
  float* ctxT = (float*)(ws + 4 * SB + (4u << 21));
  float* ksum = (float*)(ws + 4 * SB + (4u << 21) + (2u << 20));

  hipMemsetAsync(ctxT, 0, 64 * 64 * 64 * 4, stream);
  hipMemsetAsync(ksum, 0, 64 * 64 * 4, stream);

  cast_k<<<16384, 256, 0, stream>>>(x, xb, 16777216 / 4);
  cast_k<<<1024, 256, 0, stream>>>(Wq, wqb, 1048576 / 4);
  cast_k<<<1024, 256, 0, stream>>>(Wk, wkb, 1048576 / 4);
  cast_k<<<1024, 256, 0, stream>>>(Wv, wvb, 1048576 / 4);
  cast_k<<<1024, 256, 0, stream>>>(Wo, wob, 1048576 / 4);

  // QKV: (16384 x 1024) @ (3072 x 1024)^T; q row-major+elu, kT/vT transposed, ksum fused
  gemm256<1><<<768, 512, 0, stream>>>(xb, wqb, wkb, wvb, bq, bk, bv,
                                      nullptr, qb, kTb, vTb, 64, ksum);

  ctx_gemm<<<512, 64, 0, stream>>>(vTb, kTb, ctxT);

  att_gemm<<<1024, 256, 0, stream>>>(qb, ctxT, ksum);   // att -> qb (in place), D_inv fused

  // final: att @ Wo^T + bo -> f32 out
  gemm256<0><<<256, 512, 0, stream>>>(qb, wob, nullptr, nullptr, bo, nullptr, nullptr,
                                      out, nullptr, nullptr, nullptr, 64, nullptr);
}

// Round 7
// 250.949 us; speedup vs baseline: 1.2389x; 1.0457x over previous
//
#include <hip/hip_runtime.h>
#include <hip/hip_bf16.h>

typedef __attribute__((ext_vector_type(8))) short bf16x8;
typedef __attribute__((ext_vector_type(4))) float f32x4;

__device__ __forceinline__ float b2f(unsigned short u) {
  union { unsigned int i; float f; } x; x.i = ((unsigned int)u) << 16; return x.f;
}
__device__ __forceinline__ unsigned short f2b(float f) {
  union { __hip_bfloat16 h; unsigned short u; } x; x.h = __float2bfloat16(f); return x.u;
}
__device__ __forceinline__ f32x4 mfma16(bf16x8 a, bf16x8 b, f32x4 c) {
  return __builtin_amdgcn_mfma_f32_16x16x32_bf16(a, b, c, 0, 0, 0);
}
__device__ __forceinline__ void gl16(const void* g, void* l) {
  __builtin_amdgcn_global_load_lds(
      (const __attribute__((address_space(1))) unsigned int*)g,
      (__attribute__((address_space(3))) unsigned int*)l, 16, 0, 0);
}

// ---------------- cast f32 -> bf16 (vectorized) ----------------
__global__ __launch_bounds__(256) void cast_k(const float* __restrict__ src,
                                              unsigned short* __restrict__ dst, int n4) {
  int i = blockIdx.x * 256 + threadIdx.x;
  if (i >= n4) return;
  float4 v = ((const float4*)src)[i];
  ushort4 o;
  o.x = f2b(v.x); o.y = f2b(v.y); o.z = f2b(v.z); o.w = f2b(v.w);
  ((ushort4*)dst)[i] = o;
}

// =============== 256x256 8-phase bf16 GEMM (C = A * W^T), K=1024 ===============
// K-loop = the R4-proven schedule (same-phase ds_read consume, LGKM0 after
// barrier, counted vmcnt(4), setprio). Do not touch.
// MODE 0: f32 out + bias (final projection, N=1024)
// MODE 1: QKV fused (N=3072): sel=0 q -> row-major bf16 + elu+1;
//         sel=1 k -> elu+1, written TRANSPOSED [bh][d][n] + ksum atomics;
//         sel=2 v -> written TRANSPOSED [bh][d][n].
// Transposed epilogue: acc -> LDS [256 cols][256 rows] bf16 with XOR swizzle
// (byte = c*512 + ((r*2)^((c&7)<<4))), barrier, then COALESCED pass-B: each
// half-wave reads one 512B row-chunk and stores it contiguously; ksum via
// 32-lane shfl reduce (R6's strided 16B stores were the +18us regression).
#define BARX() asm volatile("s_barrier" ::: "memory")
#define LGKM0() asm volatile("s_waitcnt lgkmcnt(0)" ::: "memory")
#define WAITV4() asm volatile("s_waitcnt vmcnt(4)" ::: "memory")
#define WAITV0() asm volatile("s_waitcnt vmcnt(0)" ::: "memory")
#define P1() __builtin_amdgcn_s_setprio(1)
#define P0() __builtin_amdgcn_s_setprio(0)

#define STAGE_A(BUF, G, TAU) do { \
  gl16(gA_0 + (size_t)(G) * 65536 + (TAU) * 64, sAB + (BUF) * 32768 + (G) * 16384 + u0 * 16); \
  gl16(gA_1 + (size_t)(G) * 65536 + (TAU) * 64, sAB + (BUF) * 32768 + (G) * 16384 + u1 * 16); } while (0)
#define STAGE_B(BUF, G, TAU) do { \
  gl16(gB_0 + (size_t)(G) * 32768 + (TAU) * 64, sAB + 65536 + (BUF) * 32768 + (G) * 16384 + u0 * 16); \
  gl16(gB_1 + (size_t)(G) * 32768 + (TAU) * 64, sAB + 65536 + (BUF) * 32768 + (G) * 16384 + u1 * 16); } while (0)

#define LOAD_A(BUF, MH) do { \
  _Pragma("unroll") for (int mi = 0; mi < 4; ++mi) { \
    const char* p_ = (const char*)sAB + (BUF) * 32768 + (MH) * 16384 + aRd + mi * 2048; \
    af[mi][0] = *(const bf16x8*)(p_ + sr0); \
    af[mi][1] = *(const bf16x8*)(p_ + sr1); } } while (0)
#define LOAD_B(BUF, NH, DST) do { \
  _Pragma("unroll") for (int ni = 0; ni < 2; ++ni) { \
    const char* p_ = (const char*)sAB + 65536 + (BUF) * 32768 + (NH) * 16384 + bRd + ni * 2048; \
    DST[ni][0] = *(const bf16x8*)(p_ + sr0); \
    DST[ni][1] = *(const bf16x8*)(p_ + sr1); } } while (0)

#define QUAD(MH, NH, BF) do { \
  _Pragma("unroll") for (int mi = 0; mi < 4; ++mi) \
    _Pragma("unroll") for (int ni = 0; ni < 2; ++ni) { \
      acc[(MH) * 4 + mi][(NH) * 2 + ni] = mfma16(af[mi][0], BF[ni][0], acc[(MH) * 4 + mi][(NH) * 2 + ni]); \
      acc[(MH) * 4 + mi][(NH) * 2 + ni] = mfma16(af[mi][1], BF[ni][1], acc[(MH) * 4 + mi][(NH) * 2 + ni]); } } while (0)

template<int MODE>
__global__ __launch_bounds__(512, 2) void gemm256(
    const unsigned short* __restrict__ A,
    const unsigned short* __restrict__ W0, const unsigned short* __restrict__ W1,
    const unsigned short* __restrict__ W2,
    const float* __restrict__ bias0, const float* __restrict__ bias1, const float* __restrict__ bias2,
    float* __restrict__ outF,
    unsigned short* __restrict__ o0, unsigned short* __restrict__ o1, unsigned short* __restrict__ o2,
    int tiles_m, float* __restrict__ ksum)
{
  __shared__ char sAB[131072];
  int bid = blockIdx.x;
  int nwg = gridDim.x;
  int cpx = nwg >> 3;                       // nwg % 8 == 0 for all launches
  int sbid = (bid & 7) * cpx + (bid >> 3);  // XCD-aware swizzle (bijective)
  int tm = sbid % tiles_m, tn = sbid / tiles_m;
  int m0 = tm * 256, n0 = tn * 256;

  const unsigned short* W = W0; const float* bias = bias0; unsigned short* outB = o0;
  int sel = 0;
  if (MODE == 1) {
    sel = n0 >> 10;
    if (sel == 1) { W = W1; bias = bias1; outB = o1; }
    else if (sel == 2) { W = W2; bias = bias2; outB = o2; }
  }
  int nloc0 = (MODE == 1) ? (n0 & 1023) : n0;

  int t = threadIdx.x, w = t >> 6, l = t & 63;
  int wm = w >> 2, wn = w & 3;              // 2M x 4N waves

  // ---- staging per-thread constants (2 x 16B units per granule) ----
  int u0 = t, u1 = t + 512;
  int lr0 = u0 >> 3, lr1 = u1 >> 3;
  int sl0 = (u0 & 7) ^ (lr0 & 7), sl1 = (u1 & 7) ^ (lr1 & 7);  // inverse-swizzled src slot
  int rA0 = ((lr0 >> 6) << 7) + (lr0 & 63), rA1 = ((lr1 >> 6) << 7) + (lr1 & 63);
  int rB0 = ((lr0 >> 5) << 6) + (lr0 & 31), rB1 = ((lr1 >> 5) << 6) + (lr1 & 31);
  const unsigned short* gA_0 = A + (size_t)(m0 + rA0) * 1024 + sl0 * 8;
  const unsigned short* gA_1 = A + (size_t)(m0 + rA1) * 1024 + sl1 * 8;
  const unsigned short* gB_0 = W + (size_t)(nloc0 + rB0) * 1024 + sl0 * 8;
  const unsigned short* gB_1 = W + (size_t)(nloc0 + rB1) * 1024 + sl1 * 8;

  // ---- reader constants ----
  int aRd = (wm * 64 + (l & 15)) * 128;
  int bRd = (wn * 32 + (l & 15)) * 128;
  int sr0 = (((l >> 4) + 0) ^ (l & 7)) * 16;  // ks=0 swizzled slot
  int sr1 = (((l >> 4) + 4) ^ (l & 7)) * 16;  // ks=1

  f32x4 acc[8][4];
  f32x4 zero = {0.f, 0.f, 0.f, 0.f};
#pragma unroll
  for (int i = 0; i < 8; ++i)
#pragma unroll
    for (int jx = 0; jx < 4; ++jx) acc[i][jx] = zero;
  bf16x8 af[4][2], bf0[2][2], bf1[2][2];

  // ---- prologue: tile0 (4 granules) + tile1 (A-g0, B-g0) ----
  STAGE_A(0, 0, 0); STAGE_B(0, 0, 0); STAGE_A(0, 1, 0); STAGE_B(0, 1, 0);
  STAGE_A(1, 0, 1); STAGE_B(1, 0, 1);
  WAITV4();   // tile0 fully landed (2 granules of tile1 in flight)
  BARX();

  for (int j = 0; j < 8; ++j) {
    int t1 = 2 * j + 1;
    int t2 = (j < 7) ? (2 * j + 2) : 14;  // last iter: re-stage L2-hot tiles
    int t3 = (j < 7) ? (2 * j + 3) : 15;  // (identical bytes -> benign)
    // ph1
    LOAD_A(0, 0); LOAD_B(0, 0, bf0);
    STAGE_A(1, 1, t1);
    BARX(); LGKM0(); P1(); QUAD(0, 0, bf0); P0(); BARX();
    // ph2
    LOAD_B(0, 1, bf1);
    STAGE_B(1, 1, t1);
    BARX(); LGKM0(); P1(); QUAD(0, 1, bf1); P0(); BARX();
    // ph3
    LOAD_A(0, 1);
    STAGE_A(0, 0, t2);
    BARX(); LGKM0(); P1(); QUAD(1, 0, bf0); P0(); BARX();
    // ph4
    STAGE_B(0, 0, t2);
    BARX(); LGKM0(); P1(); QUAD(1, 1, bf1); P0(); WAITV4(); BARX();
    // ph5
    LOAD_A(1, 0); LOAD_B(1, 0, bf0);
    STAGE_A(0, 1, t2);
    BARX(); LGKM0(); P1(); QUAD(0, 0, bf0); P0(); BARX();
    // ph6
    LOAD_B(1, 1, bf1);
    STAGE_B(0, 1, t2);
    BARX(); LGKM0(); P1(); QUAD(0, 1, bf1); P0(); BARX();
    // ph7
    LOAD_A(1, 1);
    STAGE_A(1, 0, t3);
    BARX(); LGKM0(); P1(); QUAD(1, 0, bf0); P0(); BARX();
    // ph8
    STAGE_B(1, 0, t3);
    BARX(); LGKM0(); P1(); QUAD(1, 1, bf1); P0(); WAITV4(); BARX();
  }
  WAITV0();  // no global_load_lds in flight at s_endpgm / during epilogue

  // ---- epilogue ----
  if (MODE == 1 && sel >= 1) {
    // k/v: write TRANSPOSED [bh][d][n] via in-LDS 256x256 transpose.
    int b_idx = m0 >> 12;
    int nloc_h = nloc0 >> 6;
    // pass A: acc -> LDS (col-major rows, XOR-swizzled)
#pragma unroll
    for (int mq = 0; mq < 8; ++mq) {
      int r_base = wm * 128 + (mq >> 2) * 64 + (mq & 3) * 16 + ((l >> 4) << 2);
#pragma unroll
      for (int nq = 0; nq < 4; ++nq) {
        int c_loc = wn * 64 + (nq >> 1) * 32 + (nq & 1) * 16 + (l & 15);
        float bb = bias[nloc0 + c_loc];
        float v0 = acc[mq][nq][0] + bb, v1 = acc[mq][nq][1] + bb;
        float v2 = acc[mq][nq][2] + bb, v3 = acc[mq][nq][3] + bb;
        if (sel == 1) {  // elu(x)+1 for k
          v0 = (v0 > 0.0f) ? (v0 + 1.0f) : __expf(v0);
          v1 = (v1 > 0.0f) ? (v1 + 1.0f) : __expf(v1);
          v2 = (v2 > 0.0f) ? (v2 + 1.0f) : __expf(v2);
          v3 = (v3 > 0.0f) ? (v3 + 1.0f) : __expf(v3);
        }
        unsigned long long pk =
            (unsigned long long)(f2b(v0) | ((unsigned int)f2b(v1) << 16)) |
            ((unsigned long long)(f2b(v2) | ((unsigned int)f2b(v3) << 16)) << 32);
        int byte = c_loc * 512 + ((r_base * 2) ^ ((c_loc & 7) << 4));
        *(unsigned long long*)(sAB + byte) = pk;
      }
    }
    __syncthreads();
    // pass B (COALESCED): half-wave = one 512B row-chunk, stored contiguously.
#pragma unroll
    for (int qq = 0; qq < 16; ++qq) {
      int c_loc = qq * 16 + w * 2 + (l >> 5);
      int n_off = (l & 31) * 8;
      int d = c_loc & 63;
      int bh = b_idx * 16 + nloc_h + (c_loc >> 6);
      int byte = c_loc * 512 + ((n_off * 2) ^ ((c_loc & 7) << 4));
      bf16x8 ch = *(const bf16x8*)(sAB + byte);
      *(bf16x8*)(outB + (size_t)(bh * 64 + d) * 4096 + (m0 & 4095) + n_off) = ch;
      if (sel == 1) {
        float s = 0.f;
#pragma unroll
        for (int jj = 0; jj < 8; ++jj) s += b2f((unsigned short)ch[jj]);
        s += __shfl_xor(s, 1);
        s += __shfl_xor(s, 2);
        s += __shfl_xor(s, 4);
        s += __shfl_xor(s, 8);
        s += __shfl_xor(s, 16);
        if ((l & 31) == 0) atomicAdd(ksum + bh * 64 + d, s);
      }
    }
  } else {
#pragma unroll
    for (int mq = 0; mq < 8; ++mq) {
      int grow = m0 + wm * 128 + (mq >> 2) * 64 + (mq & 3) * 16 + ((l >> 4) << 2);
#pragma unroll
      for (int nq = 0; nq < 4; ++nq) {
        int gcol = n0 + wn * 64 + (nq >> 1) * 32 + (nq & 1) * 16 + (l & 15);
        if (MODE == 0) {
          float bb = bias[gcol];
#pragma unroll
          for (int r = 0; r < 4; ++r)
            outF[(size_t)(grow + r) * 1024 + gcol] = acc[mq][nq][r] + bb;
        } else {  // sel == 0: q, row-major + elu+1
          int c = gcol & 1023;
          float bb = bias[c];
#pragma unroll
          for (int r = 0; r < 4; ++r) {
            float v = acc[mq][nq][r] + bb;
            v = (v > 0.0f) ? (v + 1.0f) : __expf(v);
            outB[(size_t)(grow + r) * 1024 + c] = f2b(v);
          }
        }
      }
    }
  }
}

// ---- context: ctxT[bh][e][d] = sum_n v[n,e]*k[n,d]; 4-wave blocks, LDS reduce ----
__global__ __launch_bounds__(256) void ctx_gemm(
    const unsigned short* __restrict__ vT,  // [bh][64][4096]
    const unsigned short* __restrict__ kT,  // [bh][64][4096]
    float* __restrict__ ctxT)               // [bh][64][64]
{
  __shared__ float red[4][64 * 65];  // padded: e*65+d, conflict-light
  int bid = blockIdx.x;
  int bh = bid >> 3, ch = bid & 7;
  int t = threadIdx.x, wv = t >> 6, l = t & 63;
  int noff = ch * 512 + wv * 128 + ((l >> 4) << 3);
  const unsigned short* aB = vT + ((size_t)bh * 64 + (l & 15)) * 4096 + noff;
  const unsigned short* bB = kT + ((size_t)bh * 64 + (l & 15)) * 4096 + noff;
  f32x4 acc[4][4];
  f32x4 zero = {0.f, 0.f, 0.f, 0.f};
#pragma unroll
  for (int i = 0; i < 4; ++i)
#pragma unroll
    for (int j = 0; j < 4; ++j) acc[i][j] = zero;
  for (int ks = 0; ks < 4; ++ks) {   // 4 x 32 n per wave = 128 n
    bf16x8 av[4], bv[4];
#pragma unroll
    for (int mi = 0; mi < 4; ++mi) av[mi] = *(const bf16x8*)(aB + (size_t)mi * 16 * 4096 + ks * 32);
#pragma unroll
    for (int ni = 0; ni < 4; ++ni) bv[ni] = *(const bf16x8*)(bB + (size_t)ni * 16 * 4096 + ks * 32);
#pragma unroll
    for (int mi = 0; mi < 4; ++mi)
#pragma unroll
      for (int ni = 0; ni < 4; ++ni)
        acc[mi][ni] = mfma16(av[mi], bv[ni], acc[mi][ni]);
  }
#pragma unroll
  for (int mi = 0; mi < 4; ++mi)
#pragma unroll
    for (int ni = 0; ni < 4; ++ni)
#pragma unroll
      for (int r = 0; r < 4; ++r) {
        int e = mi * 16 + ((l >> 4) << 2) + r;
        int d = ni * 16 + (l & 15);
        red[wv][e * 65 + d] = acc[mi][ni][r];
      }
  __syncthreads();
  for (int o = t; o < 4096; o += 256) {
    int idx = (o >> 6) * 65 + (o & 63);
    float s = red[0][idx] + red[1][idx] + red[2][idx] + red[3][idx];
    atomicAdd(ctxT + (size_t)bh * 4096 + o, s);
  }
}

// ---------------- att = (q @ ctx) * D_inv, D_inv fused; written in-place into q ----------------
__global__ __launch_bounds__(256) void att_gemm(
    unsigned short* __restrict__ q,      // (16384,1024) in/out
    const float* __restrict__ ctxT,      // [bh][e][d]
    const float* __restrict__ ksum)      // [bh][64]
{
  int bid = blockIdx.x;
  int bh = bid & 63, mt = bid >> 6;
  int b = bh >> 4, h = bh & 15;
  int t = threadIdx.x, w = t >> 6, l = t & 63;
  int m0 = mt * 256 + w * 64;

  bf16x8 bfr[2][4];
  const float* cb = ctxT + (size_t)bh * 4096;
#pragma unroll
  for (int ks = 0; ks < 2; ++ks)
#pragma unroll
    for (int ni = 0; ni < 4; ++ni) {
      const float* p = cb + (ni * 16 + (l & 15)) * 64 + ks * 32 + ((l >> 4) << 3);
#pragma unroll
      for (int j = 0; j < 8; ++j) bfr[ks][ni][j] = (short)f2b(p[j]);
    }

  const float* kp = ksum + bh * 64 + ((l >> 4) << 3);
  float kp0[8], kp1[8];
#pragma unroll
  for (int j = 0; j < 8; ++j) { kp0[j] = kp[j]; kp1[j] = kp[j + 32]; }

  f32x4 acc[4][4];
  f32x4 zero = {0.f, 0.f, 0.f, 0.f};
#pragma unroll
  for (int i = 0; i < 4; ++i)
#pragma unroll
    for (int j = 0; j < 4; ++j) acc[i][j] = zero;
  float dvv[4];

  size_t rowbase = (size_t)(b * 4096 + m0 + (l & 15)) * 1024 + h * 64 + ((l >> 4) << 3);
#pragma unroll
  for (int mi = 0; mi < 4; ++mi) {
    bf16x8 av0 = *(const bf16x8*)(q + rowbase + (size_t)mi * 16 * 1024);
    bf16x8 av1 = *(const bf16x8*)(q + rowbase + (size_t)mi * 16 * 1024 + 32);
    float s = 0.f;
#pragma unroll
    for (int j = 0; j < 8; ++j) {
      s += b2f((unsigned short)av0[j]) * kp0[j];
      s += b2f((unsigned short)av1[j]) * kp1[j];
    }
    s += __shfl_xor(s, 16);
    s += __shfl_xor(s, 32);
    dvv[mi] = 1.0f / (s + 1e-6f);
#pragma unroll
    for (int ni = 0; ni < 4; ++ni) {
      acc[mi][ni] = mfma16(av0, bfr[0][ni], acc[mi][ni]);
      acc[mi][ni] = mfma16(av1, bfr[1][ni], acc[mi][ni]);
    }
  }

#pragma unroll
  for (int mi = 0; mi < 4; ++mi) {
    float sc[4];
#pragma unroll
    for (int r = 0; r < 4; ++r) sc[r] = __shfl(dvv[mi], ((l >> 4) << 2) + r);
#pragma unroll
    for (int ni = 0; ni < 4; ++ni) {
      int e = ni * 16 + (l & 15);
#pragma unroll
      for (int r = 0; r < 4; ++r) {
        int npos = m0 + mi * 16 + ((l >> 4) << 2) + r;
        q[(size_t)(b * 4096 + npos) * 1024 + h * 64 + e] = f2b(acc[mi][ni][r] * sc[r]);
      }
    }
  }
}

extern "C" void kernel_launch(void* const* d_in, const int* in_sizes, int n_in,
                              void* d_out, int out_size, void* d_ws, size_t ws_size,
                              hipStream_t stream)
{
  const float* x  = (const float*)d_in[0];
  const float* bq = (const float*)d_in[2];
  const float* bk = (const float*)d_in[4];
  const float* bv = (const float*)d_in[6];
  const float* bo = (const float*)d_in[8];
  const float* Wq = (const float*)d_in[1];
  const float* Wk = (const float*)d_in[3];
  const float* Wv = (const float*)d_in[5];
  const float* Wo = (const float*)d_in[7];
  float* out = (float*)d_out;

  char* ws = (char*)d_ws;
  const size_t SB = (size_t)16384 * 1024 * 2;  // 32 MiB slab
  const size_t NEED = 4 * SB + 4 * (1u << 21) + 2 * (1u << 20) + (1u << 14);
  if (ws_size < NEED) return;  // signature: absmax == max|ref| ~ 6.4e-2

  unsigned short* xb  = (unsigned short*)(ws);           // x bf16 (GEMM A input)
  unsigned short* qb  = (unsigned short*)(ws + SB);      // q bf16 row-major; later att
  unsigned short* kTb = (unsigned short*)(ws + 2 * SB);  // kT [bh][d][n]
  unsigned short* vTb = (unsigned short*)(ws + 3 * SB);  // vT [bh][d][n]
  unsigned short* wqb = (unsigned short*)(ws + 4 * SB);
  unsigned short* wkb = (unsigned short*)(ws + 4 * SB + (1u << 21));
  unsigned short* wvb = (unsigned short*)(ws + 4 * SB + (2u << 21));
  unsigned short* wob = (unsigned short*)(ws + 4 * SB + (3u << 21));
  float* ctxT = (float*)(ws + 4 * SB + (4u << 21));
  float* ksum = (float*)(ws + 4 * SB + (4u << 21) + (2u << 20));

  hipMemsetAsync(ctxT, 0, 64 * 64 * 64 * 4, stream);
  hipMemsetAsync(ksum, 0, 64 * 64 * 4, stream);

  cast_k<<<16384, 256, 0, stream>>>(x, xb, 16777216 / 4);
  cast_k<<<1024, 256, 0, stream>>>(Wq, wqb, 1048576 / 4);
  cast_k<<<1024, 256, 0, stream>>>(Wk, wkb, 1048576 / 4);
  cast_k<<<1024, 256, 0, stream>>>(Wv, wvb, 1048576 / 4);
  cast_k<<<1024, 256, 0, stream>>>(Wo, wob, 1048576 / 4);

  // QKV: (16384 x 1024) @ (3072 x 1024)^T; q row-major+elu, kT/vT transposed, ksum fused
  gemm256<1><<<768, 512, 0, stream>>>(xb, wqb, wkb, wvb, bq, bk, bv,
                                      nullptr, qb, kTb, vTb, 64, ksum);

  ctx_gemm<<<512, 256, 0, stream>>>(vTb, kTb, ctxT);

  att_gemm<<<1024, 256, 0, stream>>>(qb, ctxT, ksum);   // att -> qb (in place), D_inv fused

  // final: att @ Wo^T + bo -> f32 out
  gemm256<0><<<256, 512, 0, stream>>>(qb, wob, nullptr, nullptr, bo, nullptr, nullptr,
                                      out, nullptr, nullptr, nullptr, 64, nullptr);
}

// Round 8
// 229.776 us; speedup vs baseline: 1.3531x; 1.0921x over previous
//
#include <hip/hip_runtime.h>
#include <hip/hip_bf16.h>

typedef __attribute__((ext_vector_type(8))) short bf16x8;
typedef __attribute__((ext_vector_type(4))) float f32x4;

__device__ __forceinline__ float b2f(unsigned short u) {
  union { unsigned int i; float f; } x; x.i = ((unsigned int)u) << 16; return x.f;
}
__device__ __forceinline__ unsigned short f2b(float f) {
  union { __hip_bfloat16 h; unsigned short u; } x; x.h = __float2bfloat16(f); return x.u;
}
__device__ __forceinline__ f32x4 mfma16(bf16x8 a, bf16x8 b, f32x4 c) {
  return __builtin_amdgcn_mfma_f32_16x16x32_bf16(a, b, c, 0, 0, 0);
}
__device__ __forceinline__ void gl16(const void* g, void* l) {
  __builtin_amdgcn_global_load_lds(
      (const __attribute__((address_space(1))) unsigned int*)g,
      (__attribute__((address_space(3))) unsigned int*)l, 16, 0, 0);
}

// ---------------- cast f32 -> bf16 (vectorized) ----------------
__global__ __launch_bounds__(256) void cast_k(const float* __restrict__ src,
                                              unsigned short* __restrict__ dst, int n4) {
  int i = blockIdx.x * 256 + threadIdx.x;
  if (i >= n4) return;
  float4 v = ((const float4*)src)[i];
  ushort4 o;
  o.x = f2b(v.x); o.y = f2b(v.y); o.z = f2b(v.z); o.w = f2b(v.w);
  ((ushort4*)dst)[i] = o;
}

// ---------------- cast all 4 weight matrices in one launch ----------------
__global__ __launch_bounds__(256) void castw_k(
    const float* __restrict__ s0, const float* __restrict__ s1,
    const float* __restrict__ s2, const float* __restrict__ s3,
    unsigned short* __restrict__ d0, unsigned short* __restrict__ d1,
    unsigned short* __restrict__ d2, unsigned short* __restrict__ d3) {
  int seg = blockIdx.x >> 10;
  int i = (blockIdx.x & 1023) * 256 + threadIdx.x;   // 1024 blocks x 256 = 262144 float4
  const float* s = (seg == 0) ? s0 : (seg == 1) ? s1 : (seg == 2) ? s2 : s3;
  unsigned short* d = (seg == 0) ? d0 : (seg == 1) ? d1 : (seg == 2) ? d2 : d3;
  float4 v = ((const float4*)s)[i];
  ushort4 o;
  o.x = f2b(v.x); o.y = f2b(v.y); o.z = f2b(v.z); o.w = f2b(v.w);
  ((ushort4*)d)[i] = o;
}

// =============== 256x256 8-phase bf16 GEMM (C = A * W^T), K=1024 ===============
// K-loop = the R4-proven schedule (same-phase ds_read consume, LGKM0 after
// barrier, counted vmcnt(4), setprio). Do not touch.
// MODE 0: f32 out + bias; W selected per-batch: W = W0 + (m0>>12)<<20 (M_b).
// MODE 1: QKV fused (N=3072): sel=0 q row-major + elu+1; sel=1 k -> elu+1
//         TRANSPOSED [bh][d][n] + ksum; sel=2 v TRANSPOSED.
// Swizzle: tm-major within XCD (tn = sbid % tiles_n) so each XCD holds a
// 4MB A-panel set in its L2 and streams B (R7 fetch was 203MB vs ideal 38).
#define BARX() asm volatile("s_barrier" ::: "memory")
#define LGKM0() asm volatile("s_waitcnt lgkmcnt(0)" ::: "memory")
#define WAITV4() asm volatile("s_waitcnt vmcnt(4)" ::: "memory")
#define WAITV0() asm volatile("s_waitcnt vmcnt(0)" ::: "memory")
#define P1() __builtin_amdgcn_s_setprio(1)
#define P0() __builtin_amdgcn_s_setprio(0)

#define STAGE_A(BUF, G, TAU) do { \
  gl16(gA_0 + (size_t)(G) * 65536 + (TAU) * 64, sAB + (BUF) * 32768 + (G) * 16384 + u0 * 16); \
  gl16(gA_1 + (size_t)(G) * 65536 + (TAU) * 64, sAB + (BUF) * 32768 + (G) * 16384 + u1 * 16); } while (0)
#define STAGE_B(BUF, G, TAU) do { \
  gl16(gB_0 + (size_t)(G) * 32768 + (TAU) * 64, sAB + 65536 + (BUF) * 32768 + (G) * 16384 + u0 * 16); \
  gl16(gB_1 + (size_t)(G) * 32768 + (TAU) * 64, sAB + 65536 + (BUF) * 32768 + (G) * 16384 + u1 * 16); } while (0)

#define LOAD_A(BUF, MH) do { \
  _Pragma("unroll") for (int mi = 0; mi < 4; ++mi) { \
    const char* p_ = (const char*)sAB + (BUF) * 32768 + (MH) * 16384 + aRd + mi * 2048; \
    af[mi][0] = *(const bf16x8*)(p_ + sr0); \
    af[mi][1] = *(const bf16x8*)(p_ + sr1); } } while (0)
#define LOAD_B(BUF, NH, DST) do { \
  _Pragma("unroll") for (int ni = 0; ni < 2; ++ni) { \
    const char* p_ = (const char*)sAB + 65536 + (BUF) * 32768 + (NH) * 16384 + bRd + ni * 2048; \
    DST[ni][0] = *(const bf16x8*)(p_ + sr0); \
    DST[ni][1] = *(const bf16x8*)(p_ + sr1); } } while (0)

#define QUAD(MH, NH, BF) do { \
  _Pragma("unroll") for (int mi = 0; mi < 4; ++mi) \
    _Pragma("unroll") for (int ni = 0; ni < 2; ++ni) { \
      acc[(MH) * 4 + mi][(NH) * 2 + ni] = mfma16(af[mi][0], BF[ni][0], acc[(MH) * 4 + mi][(NH) * 2 + ni]); \
      acc[(MH) * 4 + mi][(NH) * 2 + ni] = mfma16(af[mi][1], BF[ni][1], acc[(MH) * 4 + mi][(NH) * 2 + ni]); } } while (0)

template<int MODE>
__global__ __launch_bounds__(512, 2) void gemm256(
    const unsigned short* __restrict__ A,
    const unsigned short* __restrict__ W0, const unsigned short* __restrict__ W1,
    const unsigned short* __restrict__ W2,
    const float* __restrict__ bias0, const float* __restrict__ bias1, const float* __restrict__ bias2,
    float* __restrict__ outF,
    unsigned short* __restrict__ o0, unsigned short* __restrict__ o1, unsigned short* __restrict__ o2,
    int tiles_n, float* __restrict__ ksum)
{
  __shared__ char sAB[131072];
  int bid = blockIdx.x;
  int nwg = gridDim.x;
  int cpx = nwg >> 3;                       // nwg % 8 == 0 for all launches
  int sbid = (bid & 7) * cpx + (bid >> 3);  // XCD-aware swizzle (bijective)
  int tn = sbid % tiles_n, tm = sbid / tiles_n;  // tm-major within XCD
  int m0 = tm * 256, n0 = tn * 256;

  const unsigned short* W = W0; const float* bias = bias0; unsigned short* outB = o0;
  int sel = 0;
  if (MODE == 1) {
    sel = n0 >> 10;
    if (sel == 1) { W = W1; bias = bias1; outB = o1; }
    else if (sel == 2) { W = W2; bias = bias2; outB = o2; }
  } else {
    W = W0 + ((size_t)(m0 >> 12) << 20);    // per-batch M_b (1M elems each)
  }
  int nloc0 = (MODE == 1) ? (n0 & 1023) : n0;

  int t = threadIdx.x, w = t >> 6, l = t & 63;
  int wm = w >> 2, wn = w & 3;              // 2M x 4N waves

  // ---- staging per-thread constants (2 x 16B units per granule) ----
  int u0 = t, u1 = t + 512;
  int lr0 = u0 >> 3, lr1 = u1 >> 3;
  int sl0 = (u0 & 7) ^ (lr0 & 7), sl1 = (u1 & 7) ^ (lr1 & 7);  // inverse-swizzled src slot
  int rA0 = ((lr0 >> 6) << 7) + (lr0 & 63), rA1 = ((lr1 >> 6) << 7) + (lr1 & 63);
  int rB0 = ((lr0 >> 5) << 6) + (lr0 & 31), rB1 = ((lr1 >> 5) << 6) + (lr1 & 31);
  const unsigned short* gA_0 = A + (size_t)(m0 + rA0) * 1024 + sl0 * 8;
  const unsigned short* gA_1 = A + (size_t)(m0 + rA1) * 1024 + sl1 * 8;
  const unsigned short* gB_0 = W + (size_t)(nloc0 + rB0) * 1024 + sl0 * 8;
  const unsigned short* gB_1 = W + (size_t)(nloc0 + rB1) * 1024 + sl1 * 8;

  // ---- reader constants ----
  int aRd = (wm * 64 + (l & 15)) * 128;
  int bRd = (wn * 32 + (l & 15)) * 128;
  int sr0 = (((l >> 4) + 0) ^ (l & 7)) * 16;  // ks=0 swizzled slot
  int sr1 = (((l >> 4) + 4) ^ (l & 7)) * 16;  // ks=1

  f32x4 acc[8][4];
  f32x4 zero = {0.f, 0.f, 0.f, 0.f};
#pragma unroll
  for (int i = 0; i < 8; ++i)
#pragma unroll
    for (int jx = 0; jx < 4; ++jx) acc[i][jx] = zero;
  bf16x8 af[4][2], bf0[2][2], bf1[2][2];

  // ---- prologue: tile0 (4 granules) + tile1 (A-g0, B-g0) ----
  STAGE_A(0, 0, 0); STAGE_B(0, 0, 0); STAGE_A(0, 1, 0); STAGE_B(0, 1, 0);
  STAGE_A(1, 0, 1); STAGE_B(1, 0, 1);
  WAITV4();   // tile0 fully landed (2 granules of tile1 in flight)
  BARX();

  for (int j = 0; j < 8; ++j) {
    int t1 = 2 * j + 1;
    int t2 = (j < 7) ? (2 * j + 2) : 14;  // last iter: re-stage L2-hot tiles
    int t3 = (j < 7) ? (2 * j + 3) : 15;  // (identical bytes -> benign)
    // ph1
    LOAD_A(0, 0); LOAD_B(0, 0, bf0);
    STAGE_A(1, 1, t1);
    BARX(); LGKM0(); P1(); QUAD(0, 0, bf0); P0(); BARX();
    // ph2
    LOAD_B(0, 1, bf1);
    STAGE_B(1, 1, t1);
    BARX(); LGKM0(); P1(); QUAD(0, 1, bf1); P0(); BARX();
    // ph3
    LOAD_A(0, 1);
    STAGE_A(0, 0, t2);
    BARX(); LGKM0(); P1(); QUAD(1, 0, bf0); P0(); BARX();
    // ph4
    STAGE_B(0, 0, t2);
    BARX(); LGKM0(); P1(); QUAD(1, 1, bf1); P0(); WAITV4(); BARX();
    // ph5
    LOAD_A(1, 0); LOAD_B(1, 0, bf0);
    STAGE_A(0, 1, t2);
    BARX(); LGKM0(); P1(); QUAD(0, 0, bf0); P0(); BARX();
    // ph6
    LOAD_B(1, 1, bf1);
    STAGE_B(0, 1, t2);
    BARX(); LGKM0(); P1(); QUAD(0, 1, bf1); P0(); BARX();
    // ph7
    LOAD_A(1, 1);
    STAGE_A(1, 0, t3);
    BARX(); LGKM0(); P1(); QUAD(1, 0, bf0); P0(); BARX();
    // ph8
    STAGE_B(1, 0, t3);
    BARX(); LGKM0(); P1(); QUAD(1, 1, bf1); P0(); WAITV4(); BARX();
  }
  WAITV0();  // no global_load_lds in flight at s_endpgm / during epilogue

  // ---- epilogue ----
  if (MODE == 1 && sel >= 1) {
    // k/v: write TRANSPOSED [bh][d][n] via in-LDS 256x256 transpose.
    int b_idx = m0 >> 12;
    int nloc_h = nloc0 >> 6;
    // pass A: acc -> LDS (col-major rows, XOR-swizzled)
#pragma unroll
    for (int mq = 0; mq < 8; ++mq) {
      int r_base = wm * 128 + (mq >> 2) * 64 + (mq & 3) * 16 + ((l >> 4) << 2);
#pragma unroll
      for (int nq = 0; nq < 4; ++nq) {
        int c_loc = wn * 64 + (nq >> 1) * 32 + (nq & 1) * 16 + (l & 15);
        float bb = bias[nloc0 + c_loc];
        float v0 = acc[mq][nq][0] + bb, v1 = acc[mq][nq][1] + bb;
        float v2 = acc[mq][nq][2] + bb, v3 = acc[mq][nq][3] + bb;
        if (sel == 1) {  // elu(x)+1 for k
          v0 = (v0 > 0.0f) ? (v0 + 1.0f) : __expf(v0);
          v1 = (v1 > 0.0f) ? (v1 + 1.0f) : __expf(v1);
          v2 = (v2 > 0.0f) ? (v2 + 1.0f) : __expf(v2);
          v3 = (v3 > 0.0f) ? (v3 + 1.0f) : __expf(v3);
        }
        unsigned long long pk =
            (unsigned long long)(f2b(v0) | ((unsigned int)f2b(v1) << 16)) |
            ((unsigned long long)(f2b(v2) | ((unsigned int)f2b(v3) << 16)) << 32);
        int byte = c_loc * 512 + ((r_base * 2) ^ ((c_loc & 7) << 4));
        *(unsigned long long*)(sAB + byte) = pk;
      }
    }
    __syncthreads();
    // pass B (COALESCED): half-wave = one 512B row-chunk, stored contiguously.
#pragma unroll
    for (int qq = 0; qq < 16; ++qq) {
      int c_loc = qq * 16 + w * 2 + (l >> 5);
      int n_off = (l & 31) * 8;
      int d = c_loc & 63;
      int bh = b_idx * 16 + nloc_h + (c_loc >> 6);
      int byte = c_loc * 512 + ((n_off * 2) ^ ((c_loc & 7) << 4));
      bf16x8 ch = *(const bf16x8*)(sAB + byte);
      *(bf16x8*)(outB + (size_t)(bh * 64 + d) * 4096 + (m0 & 4095) + n_off) = ch;
      if (sel == 1) {
        float s = 0.f;
#pragma unroll
        for (int jj = 0; jj < 8; ++jj) s += b2f((unsigned short)ch[jj]);
        s += __shfl_xor(s, 1);
        s += __shfl_xor(s, 2);
        s += __shfl_xor(s, 4);
        s += __shfl_xor(s, 8);
        s += __shfl_xor(s, 16);
        if ((l & 31) == 0) atomicAdd(ksum + bh * 64 + d, s);
      }
    }
  } else {
#pragma unroll
    for (int mq = 0; mq < 8; ++mq) {
      int grow = m0 + wm * 128 + (mq >> 2) * 64 + (mq & 3) * 16 + ((l >> 4) << 2);
#pragma unroll
      for (int nq = 0; nq < 4; ++nq) {
        int gcol = n0 + wn * 64 + (nq >> 1) * 32 + (nq & 1) * 16 + (l & 15);
        if (MODE == 0) {
          float bb = bias[gcol];
#pragma unroll
          for (int r = 0; r < 4; ++r)
            outF[(size_t)(grow + r) * 1024 + gcol] = acc[mq][nq][r] + bb;
        } else {  // sel == 0: q, row-major + elu+1
          int c = gcol & 1023;
          float bb = bias[c];
#pragma unroll
          for (int r = 0; r < 4; ++r) {
            float v = acc[mq][nq][r] + bb;
            v = (v > 0.0f) ? (v + 1.0f) : __expf(v);
            outB[(size_t)(grow + r) * 1024 + c] = f2b(v);
          }
        }
      }
    }
  }
}

// ---- context: ctxT[bh][d][v] = sum_n k[n,d]*v[n,v]; 4-wave blocks, LDS reduce ----
// (A-operand = kT so the m-dim of the output is the k-dim d; [d][v] layout
//  makes ctxwo_k's B-reads contiguous in v.)
__global__ __launch_bounds__(256) void ctx_gemm(
    const unsigned short* __restrict__ kT,  // [bh][64][4096]
    const unsigned short* __restrict__ vT,  // [bh][64][4096]
    float* __restrict__ ctxT)               // [bh][64(d)][64(v)]
{
  __shared__ float red[4][64 * 65];  // padded
  int bid = blockIdx.x;
  int bh = bid >> 3, ch = bid & 7;
  int t = threadIdx.x, wv = t >> 6, l = t & 63;
  int noff = ch * 512 + wv * 128 + ((l >> 4) << 3);
  const unsigned short* aB = kT + ((size_t)bh * 64 + (l & 15)) * 4096 + noff;
  const unsigned short* bB = vT + ((size_t)bh * 64 + (l & 15)) * 4096 + noff;
  f32x4 acc[4][4];
  f32x4 zero = {0.f, 0.f, 0.f, 0.f};
#pragma unroll
  for (int i = 0; i < 4; ++i)
#pragma unroll
    for (int j = 0; j < 4; ++j) acc[i][j] = zero;
  for (int ks = 0; ks < 4; ++ks) {   // 4 x 32 n per wave = 128 n
    bf16x8 av[4], bv[4];
#pragma unroll
    for (int mi = 0; mi < 4; ++mi) av[mi] = *(const bf16x8*)(aB + (size_t)mi * 16 * 4096 + ks * 32);
#pragma unroll
    for (int ni = 0; ni < 4; ++ni) bv[ni] = *(const bf16x8*)(bB + (size_t)ni * 16 * 4096 + ks * 32);
#pragma unroll
    for (int mi = 0; mi < 4; ++mi)
#pragma unroll
      for (int ni = 0; ni < 4; ++ni)
        acc[mi][ni] = mfma16(av[mi], bv[ni], acc[mi][ni]);
  }
#pragma unroll
  for (int mi = 0; mi < 4; ++mi)
#pragma unroll
    for (int ni = 0; ni < 4; ++ni)
#pragma unroll
      for (int r = 0; r < 4; ++r) {
        int dd = mi * 16 + ((l >> 4) << 2) + r;   // k-dim
        int vv = ni * 16 + (l & 15);              // v-dim
        red[wv][dd * 65 + vv] = acc[mi][ni][r];
      }
  __syncthreads();
  for (int o = t; o < 4096; o += 256) {
    int idx = (o >> 6) * 65 + (o & 63);
    float s = red[0][idx] + red[1][idx] + red[2][idx] + red[3][idx];
    atomicAdd(ctxT + (size_t)bh * 4096 + o, s);
  }
}

// ---- M_b[j][h*64+d] = sum_v ctx[b,h,d,v] * Wo[j, h*64+v]  (tiny per-head GEMM) ----
__global__ __launch_bounds__(1024) void ctxwo_k(
    const float* __restrict__ ctxT,         // [bh][d][v]
    const unsigned short* __restrict__ wo,  // [1024][1024] bf16
    unsigned short* __restrict__ M)         // [4][1024][1024] bf16
{
  int bh = blockIdx.x;
  int b = bh >> 4, h = bh & 15;
  int t = threadIdx.x, wv = t >> 6, l = t & 63;
  int j0 = wv * 64;

  bf16x8 af[4][2], bf[4][2];
#pragma unroll
  for (int mi = 0; mi < 4; ++mi)
#pragma unroll
    for (int ks = 0; ks < 2; ++ks)
      af[mi][ks] = *(const bf16x8*)(wo + (size_t)(j0 + mi * 16 + (l & 15)) * 1024 +
                                    h * 64 + ((l >> 4) << 3) + ks * 32);
#pragma unroll
  for (int ni = 0; ni < 4; ++ni)
#pragma unroll
    for (int ks = 0; ks < 2; ++ks) {
      const float* p = ctxT + (size_t)bh * 4096 + (ni * 16 + (l & 15)) * 64 +
                       ((l >> 4) << 3) + ks * 32;
#pragma unroll
      for (int jj = 0; jj < 8; ++jj) bf[ni][ks][jj] = (short)f2b(p[jj]);
    }

  f32x4 acc[4][4];
  f32x4 zero = {0.f, 0.f, 0.f, 0.f};
#pragma unroll
  for (int i = 0; i < 4; ++i)
#pragma unroll
    for (int j = 0; j < 4; ++j) acc[i][j] = zero;
#pragma unroll
  for (int mi = 0; mi < 4; ++mi)
#pragma unroll
    for (int ni = 0; ni < 4; ++ni) {
      acc[mi][ni] = mfma16(af[mi][0], bf[ni][0], acc[mi][ni]);
      acc[mi][ni] = mfma16(af[mi][1], bf[ni][1], acc[mi][ni]);
    }

  unsigned short* Mb = M + ((size_t)b << 20);
#pragma unroll
  for (int mi = 0; mi < 4; ++mi)
#pragma unroll
    for (int ni = 0; ni < 4; ++ni)
#pragma unroll
      for (int r = 0; r < 4; ++r) {
        int j = j0 + mi * 16 + ((l >> 4) << 2) + r;
        int d = ni * 16 + (l & 15);
        Mb[(size_t)j * 1024 + h * 64 + d] = f2b(acc[mi][ni][r]);
      }
}

// ---- q[n,hd] *= 1/(q[n,h,:].ksum[bh,:] + eps), in place ----
__global__ __launch_bounds__(256) void dinvq_k(
    unsigned short* __restrict__ q,      // (16384,1024) in/out
    const float* __restrict__ ksum)      // [bh][64]
{
  int t = threadIdx.x, wv = t >> 6, l = t & 63;
  int n = blockIdx.x * 4 + wv;
  int b = n >> 12;
  int h = l >> 2;
  unsigned short* qp = q + (size_t)n * 1024 + l * 16;
  const float* kp = ksum + (b * 16 + h) * 64 + (l & 3) * 16;
  bf16x8 v0 = *(const bf16x8*)qp;
  bf16x8 v1 = *(const bf16x8*)(qp + 8);
  float s = 0.f;
#pragma unroll
  for (int j = 0; j < 8; ++j) {
    s += b2f((unsigned short)v0[j]) * kp[j];
    s += b2f((unsigned short)v1[j]) * kp[8 + j];
  }
  s += __shfl_xor(s, 1);
  s += __shfl_xor(s, 2);
  float di = 1.0f / (s + 1e-6f);
#pragma unroll
  for (int j = 0; j < 8; ++j) {
    v0[j] = (short)f2b(b2f((unsigned short)v0[j]) * di);
    v1[j] = (short)f2b(b2f((unsigned short)v1[j]) * di);
  }
  *(bf16x8*)qp = v0;
  *(bf16x8*)(qp + 8) = v1;
}

extern "C" void kernel_launch(void* const* d_in, const int* in_sizes, int n_in,
                              void* d_out, int out_size, void* d_ws, size_t ws_size,
                              hipStream_t stream)
{
  const float* x  = (const float*)d_in[0];
  const float* bq = (const float*)d_in[2];
  const float* bk = (const float*)d_in[4];
  const float* bv = (const float*)d_in[6];
  const float* bo = (const float*)d_in[8];
  const float* Wq = (const float*)d_in[1];
  const float* Wk = (const float*)d_in[3];
  const float* Wv = (const float*)d_in[5];
  const float* Wo = (const float*)d_in[7];
  float* out = (float*)d_out;

  char* ws = (char*)d_ws;
  const size_t SB = (size_t)16384 * 1024 * 2;  // 32 MiB slab
  const size_t NEED = 4 * SB + 4 * (1u << 21) + 2 * (1u << 20) + (1u << 14);
  if (ws_size < NEED) return;  // signature: absmax == max|ref| ~ 6.4e-2

  unsigned short* xb  = (unsigned short*)(ws);           // x bf16; dead after QKV -> reused as M
  unsigned short* qb  = (unsigned short*)(ws + SB);      // q bf16 (scaled in place by dinvq)
  unsigned short* kTb = (unsigned short*)(ws + 2 * SB);  // kT [bh][d][n]
  unsigned short* vTb = (unsigned short*)(ws + 3 * SB);  // vT [bh][d][n]
  unsigned short* wqb = (unsigned short*)(ws + 4 * SB);
  unsigned short* wkb = (unsigned short*)(ws + 4 * SB + (1u << 21));
  unsigned short* wvb = (unsigned short*)(ws + 4 * SB + (2u << 21));
  unsigned short* wob = (unsigned short*)(ws + 4 * SB + (3u << 21));
  float* ctxT = (float*)(ws + 4 * SB + (4u << 21));
  float* ksum = (float*)(ws + 4 * SB + (4u << 21) + (2u << 20));
  unsigned short* Mbuf = xb;   // [4][1024][1024] bf16 = 8 MiB, overlays dead xb

  hipMemsetAsync(ctxT, 0, 64 * 64 * 64 * 4, stream);
  hipMemsetAsync(ksum, 0, 64 * 64 * 4, stream);

  cast_k<<<16384, 256, 0, stream>>>(x, xb, 16777216 / 4);
  castw_k<<<4096, 256, 0, stream>>>(Wq, Wk, Wv, Wo, wqb, wkb, wvb, wob);

  // QKV: q row-major+elu, kT/vT transposed, ksum fused
  gemm256<1><<<768, 512, 0, stream>>>(xb, wqb, wkb, wvb, bq, bk, bv,
                                      nullptr, qb, kTb, vTb, 12, ksum);

  ctx_gemm<<<512, 256, 0, stream>>>(kTb, vTb, ctxT);        // ctxT[bh][d][v]

  ctxwo_k<<<64, 1024, 0, stream>>>(ctxT, wob, Mbuf);        // M_b = ctx @ Wo^T (into xb)

  dinvq_k<<<4096, 256, 0, stream>>>(qb, ksum);              // q *= Dinv (in place)

  // final: out = q' @ M_b^T + bo  (per-batch weights)
  gemm256<0><<<256, 512, 0, stream>>>(qb, Mbuf, nullptr, nullptr, bo, nullptr, nullptr,
                                      out, nullptr, nullptr, nullptr, 4, nullptr);
}

// Round 10
// 219.969 us; speedup vs baseline: 1.4134x; 1.0446x over previous
//
#include <hip/hip_runtime.h>
#include <hip/hip_bf16.h>

typedef __attribute__((ext_vector_type(8))) short bf16x8;
typedef __attribute__((ext_vector_type(4))) float f32x4;

__device__ __forceinline__ float b2f(unsigned short u) {
  union { unsigned int i; float f; } x; x.i = ((unsigned int)u) << 16; return x.f;
}
__device__ __forceinline__ unsigned short f2b(float f) {
  union { __hip_bfloat16 h; unsigned short u; } x; x.h = __float2bfloat16(f); return x.u;
}
__device__ __forceinline__ f32x4 mfma16(bf16x8 a, bf16x8 b, f32x4 c) {
  return __builtin_amdgcn_mfma_f32_16x16x32_bf16(a, b, c, 0, 0, 0);
}
__device__ __forceinline__ void gl16(const void* g, void* l) {
  __builtin_amdgcn_global_load_lds(
      (const __attribute__((address_space(1))) unsigned int*)g,
      (__attribute__((address_space(3))) unsigned int*)l, 16, 0, 0);
}

// ---------------- cast f32 -> bf16 (vectorized) ----------------
__global__ __launch_bounds__(256) void cast_k(const float* __restrict__ src,
                                              unsigned short* __restrict__ dst, int n4) {
  int i = blockIdx.x * 256 + threadIdx.x;
  if (i >= n4) return;
  float4 v = ((const float4*)src)[i];
  ushort4 o;
  o.x = f2b(v.x); o.y = f2b(v.y); o.z = f2b(v.z); o.w = f2b(v.w);
  ((ushort4*)dst)[i] = o;
}

// ---- cast all 4 weight matrices + zero ksum in one launch ----
__global__ __launch_bounds__(256) void castw_k(
    const float* __restrict__ s0, const float* __restrict__ s1,
    const float* __restrict__ s2, const float* __restrict__ s3,
    unsigned short* __restrict__ d0, unsigned short* __restrict__ d1,
    unsigned short* __restrict__ d2, unsigned short* __restrict__ d3,
    float* __restrict__ ksum) {
  if (blockIdx.x == 4096) {   // zero ksum (64*64 f32)
    ((float4*)ksum)[threadIdx.x * 4 + 0] = make_float4(0.f, 0.f, 0.f, 0.f);
    ((float4*)ksum)[threadIdx.x * 4 + 1] = make_float4(0.f, 0.f, 0.f, 0.f);
    ((float4*)ksum)[threadIdx.x * 4 + 2] = make_float4(0.f, 0.f, 0.f, 0.f);
    ((float4*)ksum)[threadIdx.x * 4 + 3] = make_float4(0.f, 0.f, 0.f, 0.f);
    return;
  }
  int seg = blockIdx.x >> 10;
  int i = (blockIdx.x & 1023) * 256 + threadIdx.x;
  const float* s = (seg == 0) ? s0 : (seg == 1) ? s1 : (seg == 2) ? s2 : s3;
  unsigned short* d = (seg == 0) ? d0 : (seg == 1) ? d1 : (seg == 2) ? d2 : d3;
  float4 v = ((const float4*)s)[i];
  ushort4 o;
  o.x = f2b(v.x); o.y = f2b(v.y); o.z = f2b(v.z); o.w = f2b(v.w);
  ((ushort4*)d)[i] = o;
}

// =============== 256x256 8-phase bf16 GEMM (C = A * W^T), K=1024 ===============
// K-loop = R4-proven schedule + TAIL-PREFETCH: reads for phases 2/3/6/7 are
// issued at the tail of the preceding phase (after its QUAD, before its
// trailing barrier). Safety ledger (region safe-barrier vs issue point):
//   ph1-tail bf1 <- B-g1-buf0: staged prev-ph6, drained prev-ph8 vmcnt,
//     safe after prev-ph8 BARX = ph1 start  => ph1-tail OK.
//   ph2-tail af <- A-g1-buf0: staged prev-ph5, same safety => OK.
//   ph5-tail bf1 <- B-g1-buf1: staged ph2 (t1), drained ph4 vmcnt,
//     safe after ph4 BARX => ph5-tail OK.
//   ph6-tail af <- A-g1-buf1: staged ph1 (t1), same safety => OK.
// ph1/ph5's 12-read bursts stay at phase-top (their regions only become safe
// at the immediately preceding barrier). Tail reads drain at the NEXT phase's
// LGKM0 with a full barrier window of slack. asm memory fences confine
// placement to [LGKM0..BARX] (any position there is harmless).
#define BARX() asm volatile("s_barrier" ::: "memory")
#define LGKM0() asm volatile("s_waitcnt lgkmcnt(0)" ::: "memory")
#define WAITV4() asm volatile("s_waitcnt vmcnt(4)" ::: "memory")
#define WAITV0() asm volatile("s_waitcnt vmcnt(0)" ::: "memory")
#define P1() __builtin_amdgcn_s_setprio(1)
#define P0() __builtin_amdgcn_s_setprio(0)

#define STAGE_A(BUF, G, TAU) do { \
  gl16(gA_0 + (size_t)(G) * 65536 + (TAU) * 64, sAB + (BUF) * 32768 + (G) * 16384 + u0 * 16); \
  gl16(gA_1 + (size_t)(G) * 65536 + (TAU) * 64, sAB + (BUF) * 32768 + (G) * 16384 + u1 * 16); } while (0)
#define STAGE_B(BUF, G, TAU) do { \
  gl16(gB_0 + (size_t)(G) * 32768 + (TAU) * 64, sAB + 65536 + (BUF) * 32768 + (G) * 16384 + u0 * 16); \
  gl16(gB_1 + (size_t)(G) * 32768 + (TAU) * 64, sAB + 65536 + (BUF) * 32768 + (G) * 16384 + u1 * 16); } while (0)

#define LOAD_A(BUF, MH) do { \
  _Pragma("unroll") for (int mi = 0; mi < 4; ++mi) { \
    const char* p_ = (const char*)sAB + (BUF) * 32768 + (MH) * 16384 + aRd + mi * 2048; \
    af[mi][0] = *(const bf16x8*)(p_ + sr0); \
    af[mi][1] = *(const bf16x8*)(p_ + sr1); } } while (0)
#define LOAD_B(BUF, NH, DST) do { \
  _Pragma("unroll") for (int ni = 0; ni < 2; ++ni) { \
    const char* p_ = (const char*)sAB + 65536 + (BUF) * 32768 + (NH) * 16384 + bRd + ni * 2048; \
    DST[ni][0] = *(const bf16x8*)(p_ + sr0); \
    DST[ni][1] = *(const bf16x8*)(p_ + sr1); } } while (0)

#define QUAD(MH, NH, BF) do { \
  _Pragma("unroll") for (int mi = 0; mi < 4; ++mi) \
    _Pragma("unroll") for (int ni = 0; ni < 2; ++ni) { \
      acc[(MH) * 4 + mi][(NH) * 2 + ni] = mfma16(af[mi][0], BF[ni][0], acc[(MH) * 4 + mi][(NH) * 2 + ni]); \
      acc[(MH) * 4 + mi][(NH) * 2 + ni] = mfma16(af[mi][1], BF[ni][1], acc[(MH) * 4 + mi][(NH) * 2 + ni]); } } while (0)

template<int MODE>
__global__ __launch_bounds__(512, 2) void gemm256(
    const unsigned short* __restrict__ A,
    const unsigned short* __restrict__ W0, const unsigned short* __restrict__ W1,
    const unsigned short* __restrict__ W2,
    const float* __restrict__ bias0, const float* __restrict__ bias1, const float* __restrict__ bias2,
    float* __restrict__ outF,
    unsigned short* __restrict__ o0, unsigned short* __restrict__ o1, unsigned short* __restrict__ o2,
    int tiles_n, float* __restrict__ ksum)
{
  __shared__ char sAB[131072];
  int bid = blockIdx.x;
  int nwg = gridDim.x;
  int cpx = nwg >> 3;                       // nwg % 8 == 0 for all launches
  int sbid = (bid & 7) * cpx + (bid >> 3);  // XCD-aware swizzle (bijective)
  int tn = sbid % tiles_n, tm = sbid / tiles_n;  // tm-major within XCD
  int m0 = tm * 256, n0 = tn * 256;

  const unsigned short* W = W0; const float* bias = bias0; unsigned short* outB = o0;
  int sel = 0;
  if (MODE == 1) {
    sel = n0 >> 10;
    if (sel == 1) { W = W1; bias = bias1; outB = o1; }
    else if (sel == 2) { W = W2; bias = bias2; outB = o2; }
  } else {
    W = W0 + ((size_t)(m0 >> 12) << 20);    // per-batch M_b (1M elems each)
  }
  int nloc0 = (MODE == 1) ? (n0 & 1023) : n0;

  int t = threadIdx.x, w = t >> 6, l = t & 63;
  int wm = w >> 2, wn = w & 3;              // 2M x 4N waves

  // ---- staging per-thread constants (2 x 16B units per granule) ----
  int u0 = t, u1 = t + 512;
  int lr0 = u0 >> 3, lr1 = u1 >> 3;
  int sl0 = (u0 & 7) ^ (lr0 & 7), sl1 = (u1 & 7) ^ (lr1 & 7);  // inverse-swizzled src slot
  int rA0 = ((lr0 >> 6) << 7) + (lr0 & 63), rA1 = ((lr1 >> 6) << 7) + (lr1 & 63);
  int rB0 = ((lr0 >> 5) << 6) + (lr0 & 31), rB1 = ((lr1 >> 5) << 6) + (lr1 & 31);
  const unsigned short* gA_0 = A + (size_t)(m0 + rA0) * 1024 + sl0 * 8;
  const unsigned short* gA_1 = A + (size_t)(m0 + rA1) * 1024 + sl1 * 8;
  const unsigned short* gB_0 = W + (size_t)(nloc0 + rB0) * 1024 + sl0 * 8;
  const unsigned short* gB_1 = W + (size_t)(nloc0 + rB1) * 1024 + sl1 * 8;

  // ---- reader constants ----
  int aRd = (wm * 64 + (l & 15)) * 128;
  int bRd = (wn * 32 + (l & 15)) * 128;
  int sr0 = (((l >> 4) + 0) ^ (l & 7)) * 16;  // ks=0 swizzled slot
  int sr1 = (((l >> 4) + 4) ^ (l & 7)) * 16;  // ks=1

  f32x4 acc[8][4];
  f32x4 zero = {0.f, 0.f, 0.f, 0.f};
#pragma unroll
  for (int i = 0; i < 8; ++i)
#pragma unroll
    for (int jx = 0; jx < 4; ++jx) acc[i][jx] = zero;
  bf16x8 af[4][2], bf0[2][2], bf1[2][2];

  // ---- prologue: tile0 (4 granules) + tile1 (A-g0, B-g0) ----
  STAGE_A(0, 0, 0); STAGE_B(0, 0, 0); STAGE_A(0, 1, 0); STAGE_B(0, 1, 0);
  STAGE_A(1, 0, 1); STAGE_B(1, 0, 1);
  WAITV4();   // tile0 fully landed (2 granules of tile1 in flight)
  BARX();

  for (int j = 0; j < 8; ++j) {
    int t1 = 2 * j + 1;
    int t2 = (j < 7) ? (2 * j + 2) : 14;  // last iter: re-stage L2-hot tiles
    int t3 = (j < 7) ? (2 * j + 3) : 15;  // (identical bytes -> benign)
    // ph1
    LOAD_A(0, 0); LOAD_B(0, 0, bf0);
    STAGE_A(1, 1, t1);
    BARX(); LGKM0(); P1(); QUAD(0, 0, bf0); P0();
    LOAD_B(0, 1, bf1);                    // tail: feeds ph2
    BARX();
    // ph2
    STAGE_B(1, 1, t1);
    BARX(); LGKM0(); P1(); QUAD(0, 1, bf1); P0();
    LOAD_A(0, 1);                         // tail: feeds ph3
    BARX();
    // ph3
    STAGE_A(0, 0, t2);
    BARX(); LGKM0(); P1(); QUAD(1, 0, bf0); P0(); BARX();
    // ph4
    STAGE_B(0, 0, t2);
    BARX(); LGKM0(); P1(); QUAD(1, 1, bf1); P0(); WAITV4(); BARX();
    // ph5
    LOAD_A(1, 0); LOAD_B(1, 0, bf0);
    STAGE_A(0, 1, t2);
    BARX(); LGKM0(); P1(); QUAD(0, 0, bf0); P0();
    LOAD_B(1, 1, bf1);                    // tail: feeds ph6
    BARX();
    // ph6
    STAGE_B(0, 1, t2);
    BARX(); LGKM0(); P1(); QUAD(0, 1, bf1); P0();
    LOAD_A(1, 1);                         // tail: feeds ph7
    BARX();
    // ph7
    STAGE_A(1, 0, t3);
    BARX(); LGKM0(); P1(); QUAD(1, 0, bf0); P0(); BARX();
    // ph8
    STAGE_B(1, 0, t3);
    BARX(); LGKM0(); P1(); QUAD(1, 1, bf1); P0(); WAITV4(); BARX();
  }
  WAITV0();  // no global_load_lds in flight at s_endpgm / during epilogue

  // ---- epilogue ----
  if (MODE == 1 && sel >= 1) {
    // k/v: write TRANSPOSED [bh][d][n] via in-LDS 256x256 transpose.
    int b_idx = m0 >> 12;
    int nloc_h = nloc0 >> 6;
    // pass A: acc -> LDS (col-major rows, XOR-swizzled)
#pragma unroll
    for (int mq = 0; mq < 8; ++mq) {
      int r_base = wm * 128 + (mq >> 2) * 64 + (mq & 3) * 16 + ((l >> 4) << 2);
#pragma unroll
      for (int nq = 0; nq < 4; ++nq) {
        int c_loc = wn * 64 + (nq >> 1) * 32 + (nq & 1) * 16 + (l & 15);
        float bb = bias[nloc0 + c_loc];
        float v0 = acc[mq][nq][0] + bb, v1 = acc[mq][nq][1] + bb;
        float v2 = acc[mq][nq][2] + bb, v3 = acc[mq][nq][3] + bb;
        if (sel == 1) {  // elu(x)+1 for k
          v0 = (v0 > 0.0f) ? (v0 + 1.0f) : __expf(v0);
          v1 = (v1 > 0.0f) ? (v1 + 1.0f) : __expf(v1);
          v2 = (v2 > 0.0f) ? (v2 + 1.0f) : __expf(v2);
          v3 = (v3 > 0.0f) ? (v3 + 1.0f) : __expf(v3);
        }
        unsigned long long pk =
            (unsigned long long)(f2b(v0) | ((unsigned int)f2b(v1) << 16)) |
            ((unsigned long long)(f2b(v2) | ((unsigned int)f2b(v3) << 16)) << 32);
        int byte = c_loc * 512 + ((r_base * 2) ^ ((c_loc & 7) << 4));
        *(unsigned long long*)(sAB + byte) = pk;
      }
    }
    __syncthreads();
    // pass B (COALESCED): half-wave = one 512B row-chunk, stored contiguously.
#pragma unroll
    for (int qq = 0; qq < 16; ++qq) {
      int c_loc = qq * 16 + w * 2 + (l >> 5);
      int n_off = (l & 31) * 8;
      int d = c_loc & 63;
      int bh = b_idx * 16 + nloc_h + (c_loc >> 6);
      int byte = c_loc * 512 + ((n_off * 2) ^ ((c_loc & 7) << 4));
      bf16x8 ch = *(const bf16x8*)(sAB + byte);
      *(bf16x8*)(outB + (size_t)(bh * 64 + d) * 4096 + (m0 & 4095) + n_off) = ch;
      if (sel == 1) {
        float s = 0.f;
#pragma unroll
        for (int jj = 0; jj < 8; ++jj) s += b2f((unsigned short)ch[jj]);
        s += __shfl_xor(s, 1);
        s += __shfl_xor(s, 2);
        s += __shfl_xor(s, 4);
        s += __shfl_xor(s, 8);
        s += __shfl_xor(s, 16);
        if ((l & 31) == 0) atomicAdd(ksum + bh * 64 + d, s);
      }
    }
  } else {
#pragma unroll
    for (int mq = 0; mq < 8; ++mq) {
      int grow = m0 + wm * 128 + (mq >> 2) * 64 + (mq & 3) * 16 + ((l >> 4) << 2);
#pragma unroll
      for (int nq = 0; nq < 4; ++nq) {
        int gcol = n0 + wn * 64 + (nq >> 1) * 32 + (nq & 1) * 16 + (l & 15);
        if (MODE == 0) {
          float bb = bias[gcol];
#pragma unroll
          for (int r = 0; r < 4; ++r)
            outF[(size_t)(grow + r) * 1024 + gcol] = acc[mq][nq][r] + bb;
        } else {  // sel == 0: q, row-major + elu+1
          int c = gcol & 1023;
          float bb = bias[c];
#pragma unroll
          for (int r = 0; r < 4; ++r) {
            float v = acc[mq][nq][r] + bb;
            v = (v > 0.0f) ? (v + 1.0f) : __expf(v);
            outB[(size_t)(grow + r) * 1024 + c] = f2b(v);
          }
        }
      }
    }
  }
}

// ---- context partials: ctxP[(bh*8+ch)][d][v] = sum over this chunk's n ----
__global__ __launch_bounds__(256) void ctx_gemm(
    const unsigned short* __restrict__ kT,  // [bh][64][4096]
    const unsigned short* __restrict__ vT,  // [bh][64][4096]
    float* __restrict__ ctxP)               // [512][64][64] partials
{
  __shared__ float red[4][64 * 65];  // padded
  int bid = blockIdx.x;
  int bh = bid >> 3, ch = bid & 7;
  int t = threadIdx.x, wv = t >> 6, l = t & 63;
  int noff = ch * 512 + wv * 128 + ((l >> 4) << 3);
  const unsigned short* aB = kT + ((size_t)bh * 64 + (l & 15)) * 4096 + noff;
  const unsigned short* bB = vT + ((size_t)bh * 64 + (l & 15)) * 4096 + noff;
  f32x4 acc[4][4];
  f32x4 zero = {0.f, 0.f, 0.f, 0.f};
#pragma unroll
  for (int i = 0; i < 4; ++i)
#pragma unroll
    for (int j = 0; j < 4; ++j) acc[i][j] = zero;
  for (int ks = 0; ks < 4; ++ks) {   // 4 x 32 n per wave = 128 n
    bf16x8 av[4], bv[4];
#pragma unroll
    for (int mi = 0; mi < 4; ++mi) av[mi] = *(const bf16x8*)(aB + (size_t)mi * 16 * 4096 + ks * 32);
#pragma unroll
    for (int ni = 0; ni < 4; ++ni) bv[ni] = *(const bf16x8*)(bB + (size_t)ni * 16 * 4096 + ks * 32);
#pragma unroll
    for (int mi = 0; mi < 4; ++mi)
#pragma unroll
      for (int ni = 0; ni < 4; ++ni)
        acc[mi][ni] = mfma16(av[mi], bv[ni], acc[mi][ni]);
  }
#pragma unroll
  for (int mi = 0; mi < 4; ++mi)
#pragma unroll
    for (int ni = 0; ni < 4; ++ni)
#pragma unroll
      for (int r = 0; r < 4; ++r) {
        int dd = mi * 16 + ((l >> 4) << 2) + r;   // k-dim
        int vv = ni * 16 + (l & 15);              // v-dim
        red[wv][dd * 65 + vv] = acc[mi][ni][r];
      }
  __syncthreads();
  for (int o = t; o < 4096; o += 256) {
    int idx = (o >> 6) * 65 + (o & 63);
    ctxP[(size_t)bid * 4096 + o] = red[0][idx] + red[1][idx] + red[2][idx] + red[3][idx];
  }
}

// ---- M_b[j][h*64+d] = sum_v ctx[b,h,d,v] * Wo[j, h*64+v] ----
__global__ __launch_bounds__(1024) void ctxwo_k(
    const float* __restrict__ ctxP,         // [512][64][64] partials
    const unsigned short* __restrict__ wo,  // [1024][1024] bf16
    unsigned short* __restrict__ M)         // [4][1024][1024] bf16
{
  __shared__ float cs[4096];
  int bh = blockIdx.x;
  int b = bh >> 4, h = bh & 15;
  int t = threadIdx.x, wv = t >> 6, l = t & 63;
  int j0 = wv * 64;

  // sum the 8 partials into LDS
  for (int o = t; o < 4096; o += 1024) {
    float s = 0.f;
#pragma unroll
    for (int ch = 0; ch < 8; ++ch) s += ctxP[((size_t)bh * 8 + ch) * 4096 + o];
    cs[o] = s;
  }
  __syncthreads();

  bf16x8 af[4][2], bf[4][2];
#pragma unroll
  for (int mi = 0; mi < 4; ++mi)
#pragma unroll
    for (int ks = 0; ks < 2; ++ks)
      af[mi][ks] = *(const bf16x8*)(wo + (size_t)(j0 + mi * 16 + (l & 15)) * 1024 +
                                    h * 64 + ((l >> 4) << 3) + ks * 32);
#pragma unroll
  for (int ni = 0; ni < 4; ++ni)
#pragma unroll
    for (int ks = 0; ks < 2; ++ks) {
      const float* p = cs + (ni * 16 + (l & 15)) * 64 + ((l >> 4) << 3) + ks * 32;
#pragma unroll
      for (int jj = 0; jj < 8; ++jj) bf[ni][ks][jj] = (short)f2b(p[jj]);
    }

  f32x4 acc[4][4];
  f32x4 zero = {0.f, 0.f, 0.f, 0.f};
#pragma unroll
  for (int i = 0; i < 4; ++i)
#pragma unroll
    for (int j = 0; j < 4; ++j) acc[i][j] = zero;
#pragma unroll
  for (int mi = 0; mi < 4; ++mi)
#pragma unroll
    for (int ni = 0; ni < 4; ++ni) {
      acc[mi][ni] = mfma16(af[mi][0], bf[ni][0], acc[mi][ni]);
      acc[mi][ni] = mfma16(af[mi][1], bf[ni][1], acc[mi][ni]);
    }

  unsigned short* Mb = M + ((size_t)b << 20);
#pragma unroll
  for (int mi = 0; mi < 4; ++mi)
#pragma unroll
    for (int ni = 0; ni < 4; ++ni)
#pragma unroll
      for (int r = 0; r < 4; ++r) {
        int j = j0 + mi * 16 + ((l >> 4) << 2) + r;
        int d = ni * 16 + (l & 15);
        Mb[(size_t)j * 1024 + h * 64 + d] = f2b(acc[mi][ni][r]);
      }
}

// ---- q[n,hd] *= 1/(q[n,h,:].ksum[bh,:] + eps), in place ----
__global__ __launch_bounds__(256) void dinvq_k(
    unsigned short* __restrict__ q,      // (16384,1024) in/out
    const float* __restrict__ ksum)      // [bh][64]
{
  int t = threadIdx.x, wv = t >> 6, l = t & 63;
  int n = blockIdx.x * 4 + wv;
  int b = n >> 12;
  int h = l >> 2;
  unsigned short* qp = q + (size_t)n * 1024 + l * 16;
  const float* kp = ksum + (b * 16 + h) * 64 + (l & 3) * 16;
  bf16x8 v0 = *(const bf16x8*)qp;
  bf16x8 v1 = *(const bf16x8*)(qp + 8);
  float s = 0.f;
#pragma unroll
  for (int j = 0; j < 8; ++j) {
    s += b2f((unsigned short)v0[j]) * kp[j];
    s += b2f((unsigned short)v1[j]) * kp[8 + j];
  }
  s += __shfl_xor(s, 1);
  s += __shfl_xor(s, 2);
  float di = 1.0f / (s + 1e-6f);
#pragma unroll
  for (int j = 0; j < 8; ++j) {
    v0[j] = (short)f2b(b2f((unsigned short)v0[j]) * di);
    v1[j] = (short)f2b(b2f((unsigned short)v1[j]) * di);
  }
  *(bf16x8*)qp = v0;
  *(bf16x8*)(qp + 8) = v1;
}

extern "C" void kernel_launch(void* const* d_in, const int* in_sizes, int n_in,
                              void* d_out, int out_size, void* d_ws, size_t ws_size,
                              hipStream_t stream)
{
  const float* x  = (const float*)d_in[0];
  const float* bq = (const float*)d_in[2];
  const float* bk = (const float*)d_in[4];
  const float* bv = (const float*)d_in[6];
  const float* bo = (const float*)d_in[8];
  const float* Wq = (const float*)d_in[1];
  const float* Wk = (const float*)d_in[3];
  const float* Wv = (const float*)d_in[5];
  const float* Wo = (const float*)d_in[7];
  float* out = (float*)d_out;

  char* ws = (char*)d_ws;
  const size_t SB = (size_t)16384 * 1024 * 2;  // 32 MiB slab
  const size_t NEED = 4 * SB + 4 * (1u << 21) + 2 * (1u << 20) + (1u << 14);
  if (ws_size < NEED) return;  // signature: absmax == max|ref| ~ 6.4e-2

  unsigned short* xb  = (unsigned short*)(ws);           // x bf16; dead after QKV
  unsigned short* qb  = (unsigned short*)(ws + SB);      // q bf16 (scaled in place)
  unsigned short* kTb = (unsigned short*)(ws + 2 * SB);  // kT [bh][d][n]
  unsigned short* vTb = (unsigned short*)(ws + 3 * SB);  // vT [bh][d][n]
  unsigned short* wqb = (unsigned short*)(ws + 4 * SB);
  unsigned short* wkb = (unsigned short*)(ws + 4 * SB + (1u << 21));
  unsigned short* wvb = (unsigned short*)(ws + 4 * SB + (2u << 21));
  unsigned short* wob = (unsigned short*)(ws + 4 * SB + (3u << 21));
  float* ksum = (float*)(ws + 4 * SB + (4u << 21) + (2u << 20));
  unsigned short* Mbuf = xb;                       // [4][1024][1024] bf16 = 8 MiB
  float* ctxP = (float*)(ws + (8u << 20));         // [512][4096] f32 = 8 MiB (in dead xb)

  cast_k<<<16384, 256, 0, stream>>>(x, xb, 16777216 / 4);
  castw_k<<<4097, 256, 0, stream>>>(Wq, Wk, Wv, Wo, wqb, wkb, wvb, wob, ksum);

  // QKV: q row-major+elu, kT/vT transposed, ksum fused
  gemm256<1><<<768, 512, 0, stream>>>(xb, wqb, wkb, wvb, bq, bk, bv,
                                      nullptr, qb, kTb, vTb, 12, ksum);

  ctx_gemm<<<512, 256, 0, stream>>>(kTb, vTb, ctxP);        // partials [512][4096]

  ctxwo_k<<<64, 1024, 0, stream>>>(ctxP, wob, Mbuf);        // M_b = ctx @ Wo^T

  dinvq_k<<<4096, 256, 0, stream>>>(qb, ksum);              // q *= Dinv (in place)

  // final: out = q' @ M_b^T + bo  (per-batch weights)
  gemm256<0><<<256, 512, 0, stream>>>(qb, Mbuf, nullptr, nullptr, bo, nullptr, nullptr,
                                      out, nullptr, nullptr, nullptr, 4, nullptr);
}

// Round 11
// 219.920 us; speedup vs baseline: 1.4137x; 1.0002x over previous
//
#include <hip/hip_runtime.h>
#include <hip/hip_bf16.h>

typedef __attribute__((ext_vector_type(8))) short bf16x8;
typedef __attribute__((ext_vector_type(4))) float f32x4;

__device__ __forceinline__ float b2f(unsigned short u) {
  union { unsigned int i; float f; } x; x.i = ((unsigned int)u) << 16; return x.f;
}
__device__ __forceinline__ unsigned short f2b(float f) {
  union { __hip_bfloat16 h; unsigned short u; } x; x.h = __float2bfloat16(f); return x.u;
}
__device__ __forceinline__ f32x4 mfma16(bf16x8 a, bf16x8 b, f32x4 c) {
  return __builtin_amdgcn_mfma_f32_16x16x32_bf16(a, b, c, 0, 0, 0);
}
__device__ __forceinline__ void gl16(const void* g, void* l) {
  __builtin_amdgcn_global_load_lds(
      (const __attribute__((address_space(1))) unsigned int*)g,
      (__attribute__((address_space(3))) unsigned int*)l, 16, 0, 0);
}

// ---------------- cast f32 -> bf16 (vectorized) ----------------
__global__ __launch_bounds__(256) void cast_k(const float* __restrict__ src,
                                              unsigned short* __restrict__ dst, int n4) {
  int i = blockIdx.x * 256 + threadIdx.x;
  if (i >= n4) return;
  float4 v = ((const float4*)src)[i];
  ushort4 o;
  o.x = f2b(v.x); o.y = f2b(v.y); o.z = f2b(v.z); o.w = f2b(v.w);
  ((ushort4*)dst)[i] = o;
}

// ---- cast all 4 weight matrices + zero ksum in one launch ----
__global__ __launch_bounds__(256) void castw_k(
    const float* __restrict__ s0, const float* __restrict__ s1,
    const float* __restrict__ s2, const float* __restrict__ s3,
    unsigned short* __restrict__ d0, unsigned short* __restrict__ d1,
    unsigned short* __restrict__ d2, unsigned short* __restrict__ d3,
    float* __restrict__ ksum) {
  if (blockIdx.x == 4096) {   // zero ksum (64*64 f32)
    ((float4*)ksum)[threadIdx.x * 4 + 0] = make_float4(0.f, 0.f, 0.f, 0.f);
    ((float4*)ksum)[threadIdx.x * 4 + 1] = make_float4(0.f, 0.f, 0.f, 0.f);
    ((float4*)ksum)[threadIdx.x * 4 + 2] = make_float4(0.f, 0.f, 0.f, 0.f);
    ((float4*)ksum)[threadIdx.x * 4 + 3] = make_float4(0.f, 0.f, 0.f, 0.f);
    return;
  }
  int seg = blockIdx.x >> 10;
  int i = (blockIdx.x & 1023) * 256 + threadIdx.x;
  const float* s = (seg == 0) ? s0 : (seg == 1) ? s1 : (seg == 2) ? s2 : s3;
  unsigned short* d = (seg == 0) ? d0 : (seg == 1) ? d1 : (seg == 2) ? d2 : d3;
  float4 v = ((const float4*)s)[i];
  ushort4 o;
  o.x = f2b(v.x); o.y = f2b(v.y); o.z = f2b(v.z); o.w = f2b(v.w);
  ((ushort4*)d)[i] = o;
}

// =============== 256x256 8-phase bf16 GEMM (C = A * W^T), K=1024 ===============
// R11 CHANGE (single variable): barriers are now __builtin_amdgcn_s_barrier()
// and the in-loop waitcnt asms carry NO memory clobber. Rationale: opaque
// asm("s_barrier":::"memory") makes LLVM's waitcnt pass conservatively drain
// vmcnt/lgkmcnt at every barrier, defeating the counted-vmcnt pipeline
// (m201/HK use the builtin barrier for exactly this reason). Safety under
// relaxed ordering: every staged-region ds_read is separated from its
// covering vmcnt wait by a barrier INTRINSIC (loads cannot cross the fence);
// all reads feed same/next-phase QUADs so the compiler's precise waitcnt
// covers register consumption; >=2 intrinsic barriers between any region's
// last read and its re-stage. WAITV0 (once, before epilogue) KEEPS the
// memory clobber: epilogue LDS writes must not hoist above the gl16 drain.
#define BARX() __builtin_amdgcn_s_barrier()
#define LGKM0() asm volatile("s_waitcnt lgkmcnt(0)")
#define WAITV4() asm volatile("s_waitcnt vmcnt(4)")
#define WAITV0() asm volatile("s_waitcnt vmcnt(0)" ::: "memory")
#define P1() __builtin_amdgcn_s_setprio(1)
#define P0() __builtin_amdgcn_s_setprio(0)

#define STAGE_A(BUF, G, TAU) do { \
  gl16(gA_0 + (size_t)(G) * 65536 + (TAU) * 64, sAB + (BUF) * 32768 + (G) * 16384 + u0 * 16); \
  gl16(gA_1 + (size_t)(G) * 65536 + (TAU) * 64, sAB + (BUF) * 32768 + (G) * 16384 + u1 * 16); } while (0)
#define STAGE_B(BUF, G, TAU) do { \
  gl16(gB_0 + (size_t)(G) * 32768 + (TAU) * 64, sAB + 65536 + (BUF) * 32768 + (G) * 16384 + u0 * 16); \
  gl16(gB_1 + (size_t)(G) * 32768 + (TAU) * 64, sAB + 65536 + (BUF) * 32768 + (G) * 16384 + u1 * 16); } while (0)

#define LOAD_A(BUF, MH) do { \
  _Pragma("unroll") for (int mi = 0; mi < 4; ++mi) { \
    const char* p_ = (const char*)sAB + (BUF) * 32768 + (MH) * 16384 + aRd + mi * 2048; \
    af[mi][0] = *(const bf16x8*)(p_ + sr0); \
    af[mi][1] = *(const bf16x8*)(p_ + sr1); } } while (0)
#define LOAD_B(BUF, NH, DST) do { \
  _Pragma("unroll") for (int ni = 0; ni < 2; ++ni) { \
    const char* p_ = (const char*)sAB + 65536 + (BUF) * 32768 + (NH) * 16384 + bRd + ni * 2048; \
    DST[ni][0] = *(const bf16x8*)(p_ + sr0); \
    DST[ni][1] = *(const bf16x8*)(p_ + sr1); } } while (0)

#define QUAD(MH, NH, BF) do { \
  _Pragma("unroll") for (int mi = 0; mi < 4; ++mi) \
    _Pragma("unroll") for (int ni = 0; ni < 2; ++ni) { \
      acc[(MH) * 4 + mi][(NH) * 2 + ni] = mfma16(af[mi][0], BF[ni][0], acc[(MH) * 4 + mi][(NH) * 2 + ni]); \
      acc[(MH) * 4 + mi][(NH) * 2 + ni] = mfma16(af[mi][1], BF[ni][1], acc[(MH) * 4 + mi][(NH) * 2 + ni]); } } while (0)

template<int MODE>
__global__ __launch_bounds__(512, 2) void gemm256(
    const unsigned short* __restrict__ A,
    const unsigned short* __restrict__ W0, const unsigned short* __restrict__ W1,
    const unsigned short* __restrict__ W2,
    const float* __restrict__ bias0, const float* __restrict__ bias1, const float* __restrict__ bias2,
    float* __restrict__ outF,
    unsigned short* __restrict__ o0, unsigned short* __restrict__ o1, unsigned short* __restrict__ o2,
    int tiles_n, float* __restrict__ ksum)
{
  __shared__ char sAB[131072];
  int bid = blockIdx.x;
  int nwg = gridDim.x;
  int cpx = nwg >> 3;                       // nwg % 8 == 0 for all launches
  int sbid = (bid & 7) * cpx + (bid >> 3);  // XCD-aware swizzle (bijective)
  int tn = sbid % tiles_n, tm = sbid / tiles_n;  // tm-major within XCD
  int m0 = tm * 256, n0 = tn * 256;

  const unsigned short* W = W0; const float* bias = bias0; unsigned short* outB = o0;
  int sel = 0;
  if (MODE == 1) {
    sel = n0 >> 10;
    if (sel == 1) { W = W1; bias = bias1; outB = o1; }
    else if (sel == 2) { W = W2; bias = bias2; outB = o2; }
  } else {
    W = W0 + ((size_t)(m0 >> 12) << 20);    // per-batch M_b (1M elems each)
  }
  int nloc0 = (MODE == 1) ? (n0 & 1023) : n0;

  int t = threadIdx.x, w = t >> 6, l = t & 63;
  int wm = w >> 2, wn = w & 3;              // 2M x 4N waves

  // ---- staging per-thread constants (2 x 16B units per granule) ----
  int u0 = t, u1 = t + 512;
  int lr0 = u0 >> 3, lr1 = u1 >> 3;
  int sl0 = (u0 & 7) ^ (lr0 & 7), sl1 = (u1 & 7) ^ (lr1 & 7);  // inverse-swizzled src slot
  int rA0 = ((lr0 >> 6) << 7) + (lr0 & 63), rA1 = ((lr1 >> 6) << 7) + (lr1 & 63);
  int rB0 = ((lr0 >> 5) << 6) + (lr0 & 31), rB1 = ((lr1 >> 5) << 6) + (lr1 & 31);
  const unsigned short* gA_0 = A + (size_t)(m0 + rA0) * 1024 + sl0 * 8;
  const unsigned short* gA_1 = A + (size_t)(m0 + rA1) * 1024 + sl1 * 8;
  const unsigned short* gB_0 = W + (size_t)(nloc0 + rB0) * 1024 + sl0 * 8;
  const unsigned short* gB_1 = W + (size_t)(nloc0 + rB1) * 1024 + sl1 * 8;

  // ---- reader constants ----
  int aRd = (wm * 64 + (l & 15)) * 128;
  int bRd = (wn * 32 + (l & 15)) * 128;
  int sr0 = (((l >> 4) + 0) ^ (l & 7)) * 16;  // ks=0 swizzled slot
  int sr1 = (((l >> 4) + 4) ^ (l & 7)) * 16;  // ks=1

  f32x4 acc[8][4];
  f32x4 zero = {0.f, 0.f, 0.f, 0.f};
#pragma unroll
  for (int i = 0; i < 8; ++i)
#pragma unroll
    for (int jx = 0; jx < 4; ++jx) acc[i][jx] = zero;
  bf16x8 af[4][2], bf0[2][2], bf1[2][2];

  // ---- prologue: tile0 (4 granules) + tile1 (A-g0, B-g0) ----
  STAGE_A(0, 0, 0); STAGE_B(0, 0, 0); STAGE_A(0, 1, 0); STAGE_B(0, 1, 0);
  STAGE_A(1, 0, 1); STAGE_B(1, 0, 1);
  WAITV4();   // tile0 fully landed (2 granules of tile1 in flight)
  BARX();

  for (int j = 0; j < 8; ++j) {
    int t1 = 2 * j + 1;
    int t2 = (j < 7) ? (2 * j + 2) : 14;  // last iter: re-stage L2-hot tiles
    int t3 = (j < 7) ? (2 * j + 3) : 15;  // (identical bytes -> benign)
    // ph1
    LOAD_A(0, 0); LOAD_B(0, 0, bf0);
    STAGE_A(1, 1, t1);
    BARX(); LGKM0(); P1(); QUAD(0, 0, bf0); P0();
    LOAD_B(0, 1, bf1);                    // tail: feeds ph2
    BARX();
    // ph2
    STAGE_B(1, 1, t1);
    BARX(); LGKM0(); P1(); QUAD(0, 1, bf1); P0();
    LOAD_A(0, 1);                         // tail: feeds ph3
    BARX();
    // ph3
    STAGE_A(0, 0, t2);
    BARX(); LGKM0(); P1(); QUAD(1, 0, bf0); P0(); BARX();
    // ph4
    STAGE_B(0, 0, t2);
    BARX(); LGKM0(); P1(); QUAD(1, 1, bf1); P0(); WAITV4(); BARX();
    // ph5
    LOAD_A(1, 0); LOAD_B(1, 0, bf0);
    STAGE_A(0, 1, t2);
    BARX(); LGKM0(); P1(); QUAD(0, 0, bf0); P0();
    LOAD_B(1, 1, bf1);                    // tail: feeds ph6
    BARX();
    // ph6
    STAGE_B(0, 1, t2);
    BARX(); LGKM0(); P1(); QUAD(0, 1, bf1); P0();
    LOAD_A(1, 1);                         // tail: feeds ph7
    BARX();
    // ph7
    STAGE_A(1, 0, t3);
    BARX(); LGKM0(); P1(); QUAD(1, 0, bf0); P0(); BARX();
    // ph8
    STAGE_B(1, 0, t3);
    BARX(); LGKM0(); P1(); QUAD(1, 1, bf1); P0(); WAITV4(); BARX();
  }
  WAITV0();  // full drain (memory-clobber kept): epilogue overwrites sAB

  // ---- epilogue ----
  if (MODE == 1 && sel >= 1) {
    // k/v: write TRANSPOSED [bh][d][n] via in-LDS 256x256 transpose.
    int b_idx = m0 >> 12;
    int nloc_h = nloc0 >> 6;
    // pass A: acc -> LDS (col-major rows, XOR-swizzled)
#pragma unroll
    for (int mq = 0; mq < 8; ++mq) {
      int r_base = wm * 128 + (mq >> 2) * 64 + (mq & 3) * 16 + ((l >> 4) << 2);
#pragma unroll
      for (int nq = 0; nq < 4; ++nq) {
        int c_loc = wn * 64 + (nq >> 1) * 32 + (nq & 1) * 16 + (l & 15);
        float bb = bias[nloc0 + c_loc];
        float v0 = acc[mq][nq][0] + bb, v1 = acc[mq][nq][1] + bb;
        float v2 = acc[mq][nq][2] + bb, v3 = acc[mq][nq][3] + bb;
        if (sel == 1) {  // elu(x)+1 for k
          v0 = (v0 > 0.0f) ? (v0 + 1.0f) : __expf(v0);
          v1 = (v1 > 0.0f) ? (v1 + 1.0f) : __expf(v1);
          v2 = (v2 > 0.0f) ? (v2 + 1.0f) : __expf(v2);
          v3 = (v3 > 0.0f) ? (v3 + 1.0f) : __expf(v3);
        }
        unsigned long long pk =
            (unsigned long long)(f2b(v0) | ((unsigned int)f2b(v1) << 16)) |
            ((unsigned long long)(f2b(v2) | ((unsigned int)f2b(v3) << 16)) << 32);
        int byte = c_loc * 512 + ((r_base * 2) ^ ((c_loc & 7) << 4));
        *(unsigned long long*)(sAB + byte) = pk;
      }
    }
    __syncthreads();
    // pass B (COALESCED): half-wave = one 512B row-chunk, stored contiguously.
#pragma unroll
    for (int qq = 0; qq < 16; ++qq) {
      int c_loc = qq * 16 + w * 2 + (l >> 5);
      int n_off = (l & 31) * 8;
      int d = c_loc & 63;
      int bh = b_idx * 16 + nloc_h + (c_loc >> 6);
      int byte = c_loc * 512 + ((n_off * 2) ^ ((c_loc & 7) << 4));
      bf16x8 ch = *(const bf16x8*)(sAB + byte);
      *(bf16x8*)(outB + (size_t)(bh * 64 + d) * 4096 + (m0 & 4095) + n_off) = ch;
      if (sel == 1) {
        float s = 0.f;
#pragma unroll
        for (int jj = 0; jj < 8; ++jj) s += b2f((unsigned short)ch[jj]);
        s += __shfl_xor(s, 1);
        s += __shfl_xor(s, 2);
        s += __shfl_xor(s, 4);
        s += __shfl_xor(s, 8);
        s += __shfl_xor(s, 16);
        if ((l & 31) == 0) atomicAdd(ksum + bh * 64 + d, s);
      }
    }
  } else {
#pragma unroll
    for (int mq = 0; mq < 8; ++mq) {
      int grow = m0 + wm * 128 + (mq >> 2) * 64 + (mq & 3) * 16 + ((l >> 4) << 2);
#pragma unroll
      for (int nq = 0; nq < 4; ++nq) {
        int gcol = n0 + wn * 64 + (nq >> 1) * 32 + (nq & 1) * 16 + (l & 15);
        if (MODE == 0) {
          float bb = bias[gcol];
#pragma unroll
          for (int r = 0; r < 4; ++r)
            outF[(size_t)(grow + r) * 1024 + gcol] = acc[mq][nq][r] + bb;
        } else {  // sel == 0: q, row-major + elu+1
          int c = gcol & 1023;
          float bb = bias[c];
#pragma unroll
          for (int r = 0; r < 4; ++r) {
            float v = acc[mq][nq][r] + bb;
            v = (v > 0.0f) ? (v + 1.0f) : __expf(v);
            outB[(size_t)(grow + r) * 1024 + c] = f2b(v);
          }
        }
      }
    }
  }
}

// ---- context partials: ctxP[(bh*8+ch)][d][v] = sum over this chunk's n ----
__global__ __launch_bounds__(256) void ctx_gemm(
    const unsigned short* __restrict__ kT,  // [bh][64][4096]
    const unsigned short* __restrict__ vT,  // [bh][64][4096]
    float* __restrict__ ctxP)               // [512][64][64] partials
{
  __shared__ float red[4][64 * 65];  // padded
  int bid = blockIdx.x;
  int bh = bid >> 3, ch = bid & 7;
  int t = threadIdx.x, wv = t >> 6, l = t & 63;
  int noff = ch * 512 + wv * 128 + ((l >> 4) << 3);
  const unsigned short* aB = kT + ((size_t)bh * 64 + (l & 15)) * 4096 + noff;
  const unsigned short* bB = vT + ((size_t)bh * 64 + (l & 15)) * 4096 + noff;
  f32x4 acc[4][4];
  f32x4 zero = {0.f, 0.f, 0.f, 0.f};
#pragma unroll
  for (int i = 0; i < 4; ++i)
#pragma unroll
    for (int j = 0; j < 4; ++j) acc[i][j] = zero;
  for (int ks = 0; ks < 4; ++ks) {   // 4 x 32 n per wave = 128 n
    bf16x8 av[4], bv[4];
#pragma unroll
    for (int mi = 0; mi < 4; ++mi) av[mi] = *(const bf16x8*)(aB + (size_t)mi * 16 * 4096 + ks * 32);
#pragma unroll
    for (int ni = 0; ni < 4; ++ni) bv[ni] = *(const bf16x8*)(bB + (size_t)ni * 16 * 4096 + ks * 32);
#pragma unroll
    for (int mi = 0; mi < 4; ++mi)
#pragma unroll
      for (int ni = 0; ni < 4; ++ni)
        acc[mi][ni] = mfma16(av[mi], bv[ni], acc[mi][ni]);
  }
#pragma unroll
  for (int mi = 0; mi < 4; ++mi)
#pragma unroll
    for (int ni = 0; ni < 4; ++ni)
#pragma unroll
      for (int r = 0; r < 4; ++r) {
        int dd = mi * 16 + ((l >> 4) << 2) + r;   // k-dim
        int vv = ni * 16 + (l & 15);              // v-dim
        red[wv][dd * 65 + vv] = acc[mi][ni][r];
      }
  __syncthreads();
  for (int o = t; o < 4096; o += 256) {
    int idx = (o >> 6) * 65 + (o & 63);
    ctxP[(size_t)bid * 4096 + o] = red[0][idx] + red[1][idx] + red[2][idx] + red[3][idx];
  }
}

// ---- M_b[j][h*64+d] = sum_v ctx[b,h,d,v] * Wo[j, h*64+v] ----
__global__ __launch_bounds__(1024) void ctxwo_k(
    const float* __restrict__ ctxP,         // [512][64][64] partials
    const unsigned short* __restrict__ wo,  // [1024][1024] bf16
    unsigned short* __restrict__ M)         // [4][1024][1024] bf16
{
  __shared__ float cs[4096];
  int bh = blockIdx.x;
  int b = bh >> 4, h = bh & 15;
  int t = threadIdx.x, wv = t >> 6, l = t & 63;
  int j0 = wv * 64;

  // sum the 8 partials into LDS
  for (int o = t; o < 4096; o += 1024) {
    float s = 0.f;
#pragma unroll
    for (int ch = 0; ch < 8; ++ch) s += ctxP[((size_t)bh * 8 + ch) * 4096 + o];
    cs[o] = s;
  }
  __syncthreads();

  bf16x8 af[4][2], bf[4][2];
#pragma unroll
  for (int mi = 0; mi < 4; ++mi)
#pragma unroll
    for (int ks = 0; ks < 2; ++ks)
      af[mi][ks] = *(const bf16x8*)(wo + (size_t)(j0 + mi * 16 + (l & 15)) * 1024 +
                                    h * 64 + ((l >> 4) << 3) + ks * 32);
#pragma unroll
  for (int ni = 0; ni < 4; ++ni)
#pragma unroll
    for (int ks = 0; ks < 2; ++ks) {
      const float* p = cs + (ni * 16 + (l & 15)) * 64 + ((l >> 4) << 3) + ks * 32;
#pragma unroll
      for (int jj = 0; jj < 8; ++jj) bf[ni][ks][jj] = (short)f2b(p[jj]);
    }

  f32x4 acc[4][4];
  f32x4 zero = {0.f, 0.f, 0.f, 0.f};
#pragma unroll
  for (int i = 0; i < 4; ++i)
#pragma unroll
    for (int j = 0; j < 4; ++j) acc[i][j] = zero;
#pragma unroll
  for (int mi = 0; mi < 4; ++mi)
#pragma unroll
    for (int ni = 0; ni < 4; ++ni) {
      acc[mi][ni] = mfma16(af[mi][0], bf[ni][0], acc[mi][ni]);
      acc[mi][ni] = mfma16(af[mi][1], bf[ni][1], acc[mi][ni]);
    }

  unsigned short* Mb = M + ((size_t)b << 20);
#pragma unroll
  for (int mi = 0; mi < 4; ++mi)
#pragma unroll
    for (int ni = 0; ni < 4; ++ni)
#pragma unroll
      for (int r = 0; r < 4; ++r) {
        int j = j0 + mi * 16 + ((l >> 4) << 2) + r;
        int d = ni * 16 + (l & 15);
        Mb[(size_t)j * 1024 + h * 64 + d] = f2b(acc[mi][ni][r]);
      }
}

// ---- q[n,hd] *= 1/(q[n,h,:].ksum[bh,:] + eps), in place ----
__global__ __launch_bounds__(256) void dinvq_k(
    unsigned short* __restrict__ q,      // (16384,1024) in/out
    const float* __restrict__ ksum)      // [bh][64]
{
  int t = threadIdx.x, wv = t >> 6, l = t & 63;
  int n = blockIdx.x * 4 + wv;
  int b = n >> 12;
  int h = l >> 2;
  unsigned short* qp = q + (size_t)n * 1024 + l * 16;
  const float* kp = ksum + (b * 16 + h) * 64 + (l & 3) * 16;
  bf16x8 v0 = *(const bf16x8*)qp;
  bf16x8 v1 = *(const bf16x8*)(qp + 8);
  float s = 0.f;
#pragma unroll
  for (int j = 0; j < 8; ++j) {
    s += b2f((unsigned short)v0[j]) * kp[j];
    s += b2f((unsigned short)v1[j]) * kp[8 + j];
  }
  s += __shfl_xor(s, 1);
  s += __shfl_xor(s, 2);
  float di = 1.0f / (s + 1e-6f);
#pragma unroll
  for (int j = 0; j < 8; ++j) {
    v0[j] = (short)f2b(b2f((unsigned short)v0[j]) * di);
    v1[j] = (short)f2b(b2f((unsigned short)v1[j]) * di);
  }
  *(bf16x8*)qp = v0;
  *(bf16x8*)(qp + 8) = v1;
}

extern "C" void kernel_launch(void* const* d_in, const int* in_sizes, int n_in,
                              void* d_out, int out_size, void* d_ws, size_t ws_size,
                              hipStream_t stream)
{
  const float* x  = (const float*)d_in[0];
  const float* bq = (const float*)d_in[2];
  const float* bk = (const float*)d_in[4];
  const float* bv = (const float*)d_in[6];
  const float* bo = (const float*)d_in[8];
  const float* Wq = (const float*)d_in[1];
  const float* Wk = (const float*)d_in[3];
  const float* Wv = (const float*)d_in[5];
  const float* Wo = (const float*)d_in[7];
  float* out = (float*)d_out;

  char* ws = (char*)d_ws;
  const size_t SB = (size_t)16384 * 1024 * 2;  // 32 MiB slab
  const size_t NEED = 4 * SB + 4 * (1u << 21) + 2 * (1u << 20) + (1u << 14);
  if (ws_size < NEED) return;  // signature: absmax == max|ref| ~ 6.4e-2

  unsigned short* xb  = (unsigned short*)(ws);           // x bf16; dead after QKV
  unsigned short* qb  = (unsigned short*)(ws + SB);      // q bf16 (scaled in place)
  unsigned short* kTb = (unsigned short*)(ws + 2 * SB);  // kT [bh][d][n]
  unsigned short* vTb = (unsigned short*)(ws + 3 * SB);  // vT [bh][d][n]
  unsigned short* wqb = (unsigned short*)(ws + 4 * SB);
  unsigned short* wkb = (unsigned short*)(ws + 4 * SB + (1u << 21));
  unsigned short* wvb = (unsigned short*)(ws + 4 * SB + (2u << 21));
  unsigned short* wob = (unsigned short*)(ws + 4 * SB + (3u << 21));
  float* ksum = (float*)(ws + 4 * SB + (4u << 21) + (2u << 20));
  unsigned short* Mbuf = xb;                       // [4][1024][1024] bf16 = 8 MiB
  float* ctxP = (float*)(ws + (8u << 20));         // [512][4096] f32 = 8 MiB (in dead xb)

  cast_k<<<16384, 256, 0, stream>>>(x, xb, 16777216 / 4);
  castw_k<<<4097, 256, 0, stream>>>(Wq, Wk, Wv, Wo, wqb, wkb, wvb, wob, ksum);

  // QKV: q row-major+elu, kT/vT transposed, ksum fused
  gemm256<1><<<768, 512, 0, stream>>>(xb, wqb, wkb, wvb, bq, bk, bv,
                                      nullptr, qb, kTb, vTb, 12, ksum);

  ctx_gemm<<<512, 256, 0, stream>>>(kTb, vTb, ctxP);        // partials [512][4096]

  ctxwo_k<<<64, 1024, 0, stream>>>(ctxP, wob, Mbuf);        // M_b = ctx @ Wo^T

  dinvq_k<<<4096, 256, 0, stream>>>(qb, ksum);              // q *= Dinv (in place)

  // final: out = q' @ M_b^T + bo  (per-batch weights)
  gemm256<0><<<256, 512, 0, stream>>>(qb, Mbuf, nullptr, nullptr, bo, nullptr, nullptr,
                                      out, nullptr, nullptr, nullptr, 4, nullptr);
}

// Round 12
// 214.364 us; speedup vs baseline: 1.4504x; 1.0259x over previous
//
#include <hip/hip_runtime.h>
#include <hip/hip_bf16.h>

typedef __attribute__((ext_vector_type(8))) short bf16x8;
typedef __attribute__((ext_vector_type(4))) float f32x4;

__device__ __forceinline__ float b2f(unsigned short u) {
  union { unsigned int i; float f; } x; x.i = ((unsigned int)u) << 16; return x.f;
}
__device__ __forceinline__ unsigned short f2b(float f) {
  union { __hip_bfloat16 h; unsigned short u; } x; x.h = __float2bfloat16(f); return x.u;
}
__device__ __forceinline__ f32x4 mfma16(bf16x8 a, bf16x8 b, f32x4 c) {
  return __builtin_amdgcn_mfma_f32_16x16x32_bf16(a, b, c, 0, 0, 0);
}
__device__ __forceinline__ void gl16(const void* g, void* l) {
  __builtin_amdgcn_global_load_lds(
      (const __attribute__((address_space(1))) unsigned int*)g,
      (__attribute__((address_space(3))) unsigned int*)l, 16, 0, 0);
}

// ---- ALL casts + ksum zero in ONE dispatch: x (16384 blks), 4 weights (4096), ksum (1) ----
__global__ __launch_bounds__(256) void cast_all(
    const float* __restrict__ x,
    const float* __restrict__ s0, const float* __restrict__ s1,
    const float* __restrict__ s2, const float* __restrict__ s3,
    unsigned short* __restrict__ xb,
    unsigned short* __restrict__ d0, unsigned short* __restrict__ d1,
    unsigned short* __restrict__ d2, unsigned short* __restrict__ d3,
    float* __restrict__ ksum) {
  int bid = blockIdx.x;
  if (bid < 16384) {
    int i = bid * 256 + threadIdx.x;
    float4 v = ((const float4*)x)[i];
    ushort4 o;
    o.x = f2b(v.x); o.y = f2b(v.y); o.z = f2b(v.z); o.w = f2b(v.w);
    ((ushort4*)xb)[i] = o;
  } else if (bid < 20480) {
    int r = bid - 16384;
    int seg = r >> 10;
    int i = (r & 1023) * 256 + threadIdx.x;
    const float* s = (seg == 0) ? s0 : (seg == 1) ? s1 : (seg == 2) ? s2 : s3;
    unsigned short* d = (seg == 0) ? d0 : (seg == 1) ? d1 : (seg == 2) ? d2 : d3;
    float4 v = ((const float4*)s)[i];
    ushort4 o;
    o.x = f2b(v.x); o.y = f2b(v.y); o.z = f2b(v.z); o.w = f2b(v.w);
    ((ushort4*)d)[i] = o;
  } else {
    ((float4*)ksum)[threadIdx.x * 4 + 0] = make_float4(0.f, 0.f, 0.f, 0.f);
    ((float4*)ksum)[threadIdx.x * 4 + 1] = make_float4(0.f, 0.f, 0.f, 0.f);
    ((float4*)ksum)[threadIdx.x * 4 + 2] = make_float4(0.f, 0.f, 0.f, 0.f);
    ((float4*)ksum)[threadIdx.x * 4 + 3] = make_float4(0.f, 0.f, 0.f, 0.f);
  }
}

// =============== 256x256 8-phase bf16 GEMM (C = A * W^T), K=1024 ===============
// R12 CHANGE: ONE barrier per phase (trailing only). The leading barrier was
// redundant: QUAD reads registers (not LDS), so the only hazards are
//  (a) stage-after-read  — enforced by the trailing-barrier chain (a wave
//      passes trailing-BARX(p) only after its own LGKM0(p) retired its reads);
//  (b) read-after-stage  — enforced by WAITV4 (ph4/ph8) + the trailing BARX.
// Removing the leading barrier lets waves stagger inside a phase: one wave's
// MFMA overlaps another's ds_read drain (the lockstep was serializing
// 621 cyc MFMA + ~580 cyc LDS per phase). vmcnt ledger identical to R4.
// Loop exit: WAITV0 + BARX before epilogue (closes a latent race where one
// wave's epilogue LDS writes could precede another wave's in-flight
// tile-14/15 re-stage landing).
#define BARX() __builtin_amdgcn_s_barrier()
#define LGKM0() asm volatile("s_waitcnt lgkmcnt(0)")
#define WAITV4() asm volatile("s_waitcnt vmcnt(4)")
#define WAITV0() asm volatile("s_waitcnt vmcnt(0)" ::: "memory")
#define P1() __builtin_amdgcn_s_setprio(1)
#define P0() __builtin_amdgcn_s_setprio(0)

#define STAGE_A(BUF, G, TAU) do { \
  gl16(gA_0 + (size_t)(G) * 65536 + (TAU) * 64, sAB + (BUF) * 32768 + (G) * 16384 + u0 * 16); \
  gl16(gA_1 + (size_t)(G) * 65536 + (TAU) * 64, sAB + (BUF) * 32768 + (G) * 16384 + u1 * 16); } while (0)
#define STAGE_B(BUF, G, TAU) do { \
  gl16(gB_0 + (size_t)(G) * 32768 + (TAU) * 64, sAB + 65536 + (BUF) * 32768 + (G) * 16384 + u0 * 16); \
  gl16(gB_1 + (size_t)(G) * 32768 + (TAU) * 64, sAB + 65536 + (BUF) * 32768 + (G) * 16384 + u1 * 16); } while (0)

#define LOAD_A(BUF, MH) do { \
  _Pragma("unroll") for (int mi = 0; mi < 4; ++mi) { \
    const char* p_ = (const char*)sAB + (BUF) * 32768 + (MH) * 16384 + aRd + mi * 2048; \
    af[mi][0] = *(const bf16x8*)(p_ + sr0); \
    af[mi][1] = *(const bf16x8*)(p_ + sr1); } } while (0)
#define LOAD_B(BUF, NH, DST) do { \
  _Pragma("unroll") for (int ni = 0; ni < 2; ++ni) { \
    const char* p_ = (const char*)sAB + 65536 + (BUF) * 32768 + (NH) * 16384 + bRd + ni * 2048; \
    DST[ni][0] = *(const bf16x8*)(p_ + sr0); \
    DST[ni][1] = *(const bf16x8*)(p_ + sr1); } } while (0)

#define QUAD(MH, NH, BF) do { \
  _Pragma("unroll") for (int mi = 0; mi < 4; ++mi) \
    _Pragma("unroll") for (int ni = 0; ni < 2; ++ni) { \
      acc[(MH) * 4 + mi][(NH) * 2 + ni] = mfma16(af[mi][0], BF[ni][0], acc[(MH) * 4 + mi][(NH) * 2 + ni]); \
      acc[(MH) * 4 + mi][(NH) * 2 + ni] = mfma16(af[mi][1], BF[ni][1], acc[(MH) * 4 + mi][(NH) * 2 + ni]); } } while (0)

template<int MODE>
__global__ __launch_bounds__(512, 2) void gemm256(
    const unsigned short* __restrict__ A,
    const unsigned short* __restrict__ W0, const unsigned short* __restrict__ W1,
    const unsigned short* __restrict__ W2,
    const float* __restrict__ bias0, const float* __restrict__ bias1, const float* __restrict__ bias2,
    float* __restrict__ outF,
    unsigned short* __restrict__ o0, unsigned short* __restrict__ o1, unsigned short* __restrict__ o2,
    int tiles_n, float* __restrict__ ksum)
{
  __shared__ char sAB[131072];
  int bid = blockIdx.x;
  int nwg = gridDim.x;
  int cpx = nwg >> 3;                       // nwg % 8 == 0 for all launches
  int sbid = (bid & 7) * cpx + (bid >> 3);  // XCD-aware swizzle (bijective)
  int tn = sbid % tiles_n, tm = sbid / tiles_n;  // tm-major within XCD
  int m0 = tm * 256, n0 = tn * 256;

  const unsigned short* W = W0; const float* bias = bias0; unsigned short* outB = o0;
  int sel = 0;
  if (MODE == 1) {
    sel = n0 >> 10;
    if (sel == 1) { W = W1; bias = bias1; outB = o1; }
    else if (sel == 2) { W = W2; bias = bias2; outB = o2; }
  } else {
    W = W0 + ((size_t)(m0 >> 12) << 20);    // per-batch M_b (1M elems each)
  }
  int nloc0 = (MODE == 1) ? (n0 & 1023) : n0;

  int t = threadIdx.x, w = t >> 6, l = t & 63;
  int wm = w >> 2, wn = w & 3;              // 2M x 4N waves

  // ---- staging per-thread constants (2 x 16B units per granule) ----
  int u0 = t, u1 = t + 512;
  int lr0 = u0 >> 3, lr1 = u1 >> 3;
  int sl0 = (u0 & 7) ^ (lr0 & 7), sl1 = (u1 & 7) ^ (lr1 & 7);  // inverse-swizzled src slot
  int rA0 = ((lr0 >> 6) << 7) + (lr0 & 63), rA1 = ((lr1 >> 6) << 7) + (lr1 & 63);
  int rB0 = ((lr0 >> 5) << 6) + (lr0 & 31), rB1 = ((lr1 >> 5) << 6) + (lr1 & 31);
  const unsigned short* gA_0 = A + (size_t)(m0 + rA0) * 1024 + sl0 * 8;
  const unsigned short* gA_1 = A + (size_t)(m0 + rA1) * 1024 + sl1 * 8;
  const unsigned short* gB_0 = W + (size_t)(nloc0 + rB0) * 1024 + sl0 * 8;
  const unsigned short* gB_1 = W + (size_t)(nloc0 + rB1) * 1024 + sl1 * 8;

  // ---- reader constants ----
  int aRd = (wm * 64 + (l & 15)) * 128;
  int bRd = (wn * 32 + (l & 15)) * 128;
  int sr0 = (((l >> 4) + 0) ^ (l & 7)) * 16;  // ks=0 swizzled slot
  int sr1 = (((l >> 4) + 4) ^ (l & 7)) * 16;  // ks=1

  f32x4 acc[8][4];
  f32x4 zero = {0.f, 0.f, 0.f, 0.f};
#pragma unroll
  for (int i = 0; i < 8; ++i)
#pragma unroll
    for (int jx = 0; jx < 4; ++jx) acc[i][jx] = zero;
  bf16x8 af[4][2], bf0[2][2], bf1[2][2];

  // ---- prologue: tile0 (4 granules) + tile1 (A-g0, B-g0) ----
  STAGE_A(0, 0, 0); STAGE_B(0, 0, 0); STAGE_A(0, 1, 0); STAGE_B(0, 1, 0);
  STAGE_A(1, 0, 1); STAGE_B(1, 0, 1);
  WAITV4();   // tile0 fully landed (2 granules of tile1 in flight)
  BARX();

  for (int j = 0; j < 8; ++j) {
    int t1 = 2 * j + 1;
    int t2 = (j < 7) ? (2 * j + 2) : 14;  // last iter: re-stage L2-hot tiles
    int t3 = (j < 7) ? (2 * j + 3) : 15;  // (identical bytes -> benign)
    // ph1
    LOAD_A(0, 0); LOAD_B(0, 0, bf0);
    STAGE_A(1, 1, t1);
    LGKM0(); P1(); QUAD(0, 0, bf0); P0();
    LOAD_B(0, 1, bf1);                    // tail: feeds ph2
    BARX();
    // ph2
    STAGE_B(1, 1, t1);
    LGKM0(); P1(); QUAD(0, 1, bf1); P0();
    LOAD_A(0, 1);                         // tail: feeds ph3
    BARX();
    // ph3
    STAGE_A(0, 0, t2);
    LGKM0(); P1(); QUAD(1, 0, bf0); P0(); BARX();
    // ph4
    STAGE_B(0, 0, t2);
    LGKM0(); P1(); QUAD(1, 1, bf1); P0(); WAITV4(); BARX();
    // ph5
    LOAD_A(1, 0); LOAD_B(1, 0, bf0);
    STAGE_A(0, 1, t2);
    LGKM0(); P1(); QUAD(0, 0, bf0); P0();
    LOAD_B(1, 1, bf1);                    // tail: feeds ph6
    BARX();
    // ph6
    STAGE_B(0, 1, t2);
    LGKM0(); P1(); QUAD(0, 1, bf1); P0();
    LOAD_A(1, 1);                         // tail: feeds ph7
    BARX();
    // ph7
    STAGE_A(1, 0, t3);
    LGKM0(); P1(); QUAD(1, 0, bf0); P0(); BARX();
    // ph8
    STAGE_B(1, 0, t3);
    LGKM0(); P1(); QUAD(1, 1, bf1); P0(); WAITV4(); BARX();
  }
  WAITV0();  // drain all gl16 before epilogue overwrites sAB
  BARX();    // ...and make that drain visible workgroup-wide

  // ---- epilogue ----
  if (MODE == 1 && sel >= 1) {
    // k/v: write TRANSPOSED [bh][d][n] via in-LDS 256x256 transpose.
    int b_idx = m0 >> 12;
    int nloc_h = nloc0 >> 6;
    // pass A: acc -> LDS (col-major rows, XOR-swizzled)
#pragma unroll
    for (int mq = 0; mq < 8; ++mq) {
      int r_base = wm * 128 + (mq >> 2) * 64 + (mq & 3) * 16 + ((l >> 4) << 2);
#pragma unroll
      for (int nq = 0; nq < 4; ++nq) {
        int c_loc = wn * 64 + (nq >> 1) * 32 + (nq & 1) * 16 + (l & 15);
        float bb = bias[nloc0 + c_loc];
        float v0 = acc[mq][nq][0] + bb, v1 = acc[mq][nq][1] + bb;
        float v2 = acc[mq][nq][2] + bb, v3 = acc[mq][nq][3] + bb;
        if (sel == 1) {  // elu(x)+1 for k
          v0 = (v0 > 0.0f) ? (v0 + 1.0f) : __expf(v0);
          v1 = (v1 > 0.0f) ? (v1 + 1.0f) : __expf(v1);
          v2 = (v2 > 0.0f) ? (v2 + 1.0f) : __expf(v2);
          v3 = (v3 > 0.0f) ? (v3 + 1.0f) : __expf(v3);
        }
        unsigned long long pk =
            (unsigned long long)(f2b(v0) | ((unsigned int)f2b(v1) << 16)) |
            ((unsigned long long)(f2b(v2) | ((unsigned int)f2b(v3) << 16)) << 32);
        int byte = c_loc * 512 + ((r_base * 2) ^ ((c_loc & 7) << 4));
        *(unsigned long long*)(sAB + byte) = pk;
      }
    }
    __syncthreads();
    // pass B (COALESCED): half-wave = one 512B row-chunk, stored contiguously.
#pragma unroll
    for (int qq = 0; qq < 16; ++qq) {
      int c_loc = qq * 16 + w * 2 + (l >> 5);
      int n_off = (l & 31) * 8;
      int d = c_loc & 63;
      int bh = b_idx * 16 + nloc_h + (c_loc >> 6);
      int byte = c_loc * 512 + ((n_off * 2) ^ ((c_loc & 7) << 4));
      bf16x8 ch = *(const bf16x8*)(sAB + byte);
      *(bf16x8*)(outB + (size_t)(bh * 64 + d) * 4096 + (m0 & 4095) + n_off) = ch;
      if (sel == 1) {
        float s = 0.f;
#pragma unroll
        for (int jj = 0; jj < 8; ++jj) s += b2f((unsigned short)ch[jj]);
        s += __shfl_xor(s, 1);
        s += __shfl_xor(s, 2);
        s += __shfl_xor(s, 4);
        s += __shfl_xor(s, 8);
        s += __shfl_xor(s, 16);
        if ((l & 31) == 0) atomicAdd(ksum + bh * 64 + d, s);
      }
    }
  } else {
#pragma unroll
    for (int mq = 0; mq < 8; ++mq) {
      int grow = m0 + wm * 128 + (mq >> 2) * 64 + (mq & 3) * 16 + ((l >> 4) << 2);
#pragma unroll
      for (int nq = 0; nq < 4; ++nq) {
        int gcol = n0 + wn * 64 + (nq >> 1) * 32 + (nq & 1) * 16 + (l & 15);
        if (MODE == 0) {
          float bb = bias[gcol];
#pragma unroll
          for (int r = 0; r < 4; ++r)
            outF[(size_t)(grow + r) * 1024 + gcol] = acc[mq][nq][r] + bb;
        } else {  // sel == 0: q, row-major + elu+1
          int c = gcol & 1023;
          float bb = bias[c];
#pragma unroll
          for (int r = 0; r < 4; ++r) {
            float v = acc[mq][nq][r] + bb;
            v = (v > 0.0f) ? (v + 1.0f) : __expf(v);
            outB[(size_t)(grow + r) * 1024 + c] = f2b(v);
          }
        }
      }
    }
  }
}

// ---- MERGED: ctx partials (bid<512) + dinvq (bid 512..4607) ----
__global__ __launch_bounds__(256) void ctx_dinv_k(
    const unsigned short* __restrict__ kT,  // [bh][64][4096]
    const unsigned short* __restrict__ vT,  // [bh][64][4096]
    float* __restrict__ ctxP,               // [512][64][64] partials
    unsigned short* __restrict__ q,         // (16384,1024) in/out
    const float* __restrict__ ksum)         // [bh][64]
{
  __shared__ float red[4][64 * 65];  // padded
  int bid = blockIdx.x;
  int t = threadIdx.x, wv = t >> 6, l = t & 63;
  if (bid >= 512) {
    // ---- dinvq: q[n,hd] *= 1/(q[n,h,:].ksum + eps) ----
    int n = (bid - 512) * 4 + wv;
    int b = n >> 12;
    int h = l >> 2;
    unsigned short* qp = q + (size_t)n * 1024 + l * 16;
    const float* kp = ksum + (b * 16 + h) * 64 + (l & 3) * 16;
    bf16x8 v0 = *(const bf16x8*)qp;
    bf16x8 v1 = *(const bf16x8*)(qp + 8);
    float s = 0.f;
#pragma unroll
    for (int j = 0; j < 8; ++j) {
      s += b2f((unsigned short)v0[j]) * kp[j];
      s += b2f((unsigned short)v1[j]) * kp[8 + j];
    }
    s += __shfl_xor(s, 1);
    s += __shfl_xor(s, 2);
    float di = 1.0f / (s + 1e-6f);
#pragma unroll
    for (int j = 0; j < 8; ++j) {
      v0[j] = (short)f2b(b2f((unsigned short)v0[j]) * di);
      v1[j] = (short)f2b(b2f((unsigned short)v1[j]) * di);
    }
    *(bf16x8*)qp = v0;
    *(bf16x8*)(qp + 8) = v1;
    return;
  }
  // ---- ctx: ctxP[(bh*8+ch)][d][v] = sum over this chunk's n ----
  int bh = bid >> 3, ch = bid & 7;
  int noff = ch * 512 + wv * 128 + ((l >> 4) << 3);
  const unsigned short* aB = kT + ((size_t)bh * 64 + (l & 15)) * 4096 + noff;
  const unsigned short* bB = vT + ((size_t)bh * 64 + (l & 15)) * 4096 + noff;
  f32x4 acc[4][4];
  f32x4 zero = {0.f, 0.f, 0.f, 0.f};
#pragma unroll
  for (int i = 0; i < 4; ++i)
#pragma unroll
    for (int j = 0; j < 4; ++j) acc[i][j] = zero;
  for (int ks = 0; ks < 4; ++ks) {   // 4 x 32 n per wave = 128 n
    bf16x8 av[4], bv[4];
#pragma unroll
    for (int mi = 0; mi < 4; ++mi) av[mi] = *(const bf16x8*)(aB + (size_t)mi * 16 * 4096 + ks * 32);
#pragma unroll
    for (int ni = 0; ni < 4; ++ni) bv[ni] = *(const bf16x8*)(bB + (size_t)ni * 16 * 4096 + ks * 32);
#pragma unroll
    for (int mi = 0; mi < 4; ++mi)
#pragma unroll
      for (int ni = 0; ni < 4; ++ni)
        acc[mi][ni] = mfma16(av[mi], bv[ni], acc[mi][ni]);
  }
#pragma unroll
  for (int mi = 0; mi < 4; ++mi)
#pragma unroll
    for (int ni = 0; ni < 4; ++ni)
#pragma unroll
      for (int r = 0; r < 4; ++r) {
        int dd = mi * 16 + ((l >> 4) << 2) + r;   // k-dim
        int vv = ni * 16 + (l & 15);              // v-dim
        red[wv][dd * 65 + vv] = acc[mi][ni][r];
      }
  __syncthreads();
  for (int o = t; o < 4096; o += 256) {
    int idx = (o >> 6) * 65 + (o & 63);
    ctxP[(size_t)bid * 4096 + o] = red[0][idx] + red[1][idx] + red[2][idx] + red[3][idx];
  }
}

// ---- M_b[j][h*64+d] = sum_v ctx[b,h,d,v] * Wo[j, h*64+v] ----
__global__ __launch_bounds__(1024) void ctxwo_k(
    const float* __restrict__ ctxP,         // [512][64][64] partials
    const unsigned short* __restrict__ wo,  // [1024][1024] bf16
    unsigned short* __restrict__ M)         // [4][1024][1024] bf16
{
  __shared__ float cs[4096];
  int bh = blockIdx.x;
  int b = bh >> 4, h = bh & 15;
  int t = threadIdx.x, wv = t >> 6, l = t & 63;
  int j0 = wv * 64;

  // sum the 8 partials into LDS
  for (int o = t; o < 4096; o += 1024) {
    float s = 0.f;
#pragma unroll
    for (int ch = 0; ch < 8; ++ch) s += ctxP[((size_t)bh * 8 + ch) * 4096 + o];
    cs[o] = s;
  }
  __syncthreads();

  bf16x8 af[4][2], bf[4][2];
#pragma unroll
  for (int mi = 0; mi < 4; ++mi)
#pragma unroll
    for (int ks = 0; ks < 2; ++ks)
      af[mi][ks] = *(const bf16x8*)(wo + (size_t)(j0 + mi * 16 + (l & 15)) * 1024 +
                                    h * 64 + ((l >> 4) << 3) + ks * 32);
#pragma unroll
  for (int ni = 0; ni < 4; ++ni)
#pragma unroll
    for (int ks = 0; ks < 2; ++ks) {
      const float* p = cs + (ni * 16 + (l & 15)) * 64 + ((l >> 4) << 3) + ks * 32;
#pragma unroll
      for (int jj = 0; jj < 8; ++jj) bf[ni][ks][jj] = (short)f2b(p[jj]);
    }

  f32x4 acc[4][4];
  f32x4 zero = {0.f, 0.f, 0.f, 0.f};
#pragma unroll
  for (int i = 0; i < 4; ++i)
#pragma unroll
    for (int j = 0; j < 4; ++j) acc[i][j] = zero;
#pragma unroll
  for (int mi = 0; mi < 4; ++mi)
#pragma unroll
    for (int ni = 0; ni < 4; ++ni) {
      acc[mi][ni] = mfma16(af[mi][0], bf[ni][0], acc[mi][ni]);
      acc[mi][ni] = mfma16(af[mi][1], bf[ni][1], acc[mi][ni]);
    }

  unsigned short* Mb = M + ((size_t)b << 20);
#pragma unroll
  for (int mi = 0; mi < 4; ++mi)
#pragma unroll
    for (int ni = 0; ni < 4; ++ni)
#pragma unroll
      for (int r = 0; r < 4; ++r) {
        int j = j0 + mi * 16 + ((l >> 4) << 2) + r;
        int d = ni * 16 + (l & 15);
        Mb[(size_t)j * 1024 + h * 64 + d] = f2b(acc[mi][ni][r]);
      }
}

extern "C" void kernel_launch(void* const* d_in, const int* in_sizes, int n_in,
                              void* d_out, int out_size, void* d_ws, size_t ws_size,
                              hipStream_t stream)
{
  const float* x  = (const float*)d_in[0];
  const float* bq = (const float*)d_in[2];
  const float* bk = (const float*)d_in[4];
  const float* bv = (const float*)d_in[6];
  const float* bo = (const float*)d_in[8];
  const float* Wq = (const float*)d_in[1];
  const float* Wk = (const float*)d_in[3];
  const float* Wv = (const float*)d_in[5];
  const float* Wo = (const float*)d_in[7];
  float* out = (float*)d_out;

  char* ws = (char*)d_ws;
  const size_t SB = (size_t)16384 * 1024 * 2;  // 32 MiB slab
  const size_t NEED = 4 * SB + 4 * (1u << 21) + 2 * (1u << 20) + (1u << 14);
  if (ws_size < NEED) return;  // signature: absmax == max|ref| ~ 6.4e-2

  unsigned short* xb  = (unsigned short*)(ws);           // x bf16; dead after QKV
  unsigned short* qb  = (unsigned short*)(ws + SB);      // q bf16 (scaled in place)
  unsigned short* kTb = (unsigned short*)(ws + 2 * SB);  // kT [bh][d][n]
  unsigned short* vTb = (unsigned short*)(ws + 3 * SB);  // vT [bh][d][n]
  unsigned short* wqb = (unsigned short*)(ws + 4 * SB);
  unsigned short* wkb = (unsigned short*)(ws + 4 * SB + (1u << 21));
  unsigned short* wvb = (unsigned short*)(ws + 4 * SB + (2u << 21));
  unsigned short* wob = (unsigned short*)(ws + 4 * SB + (3u << 21));
  float* ksum = (float*)(ws + 4 * SB + (4u << 21) + (2u << 20));
  unsigned short* Mbuf = xb;                       // [4][1024][1024] bf16 = 8 MiB
  float* ctxP = (float*)(ws + (8u << 20));         // [512][4096] f32 = 8 MiB (in dead xb)

  cast_all<<<20481, 256, 0, stream>>>(x, Wq, Wk, Wv, Wo, xb, wqb, wkb, wvb, wob, ksum);

  // QKV: q row-major+elu, kT/vT transposed, ksum fused
  gemm256<1><<<768, 512, 0, stream>>>(xb, wqb, wkb, wvb, bq, bk, bv,
                                      nullptr, qb, kTb, vTb, 12, ksum);

  // ctx partials + q *= Dinv, one dispatch
  ctx_dinv_k<<<4608, 256, 0, stream>>>(kTb, vTb, ctxP, qb, ksum);

  ctxwo_k<<<64, 1024, 0, stream>>>(ctxP, wob, Mbuf);        // M_b = ctx @ Wo^T

  // final: out = q' @ M_b^T + bo  (per-batch weights)
  gemm256<0><<<256, 512, 0, stream>>>(qb, Mbuf, nullptr, nullptr, bo, nullptr, nullptr,
                                      out, nullptr, nullptr, nullptr, 4, nullptr);
}